// Round 2
// baseline (3006.278 us; speedup 1.0000x reference)
//
#include <hip/hip_runtime.h>
#include <math.h>

#define B_   4
#define T_   2048
#define D_   512
#define TOK  (B_*T_)      // 8192 tokens
#define TL_  2045         // N_BLOCKS*(T//N_BLOCKS) = 5*409

// softmax(...).mean(axis=-1) over the SAME axis == 1/N_BLOCKS identically.
#define GATE 0.2f

// ------------------------------------------------------------------
// xf = 0.2 * x for t < 2045, else 0
__global__ void gate_kernel(const float* __restrict__ x, float* __restrict__ xf){
    int idx = blockIdx.x*256 + threadIdx.x;
    int t = (idx / D_) % T_;
    xf[idx] = (t < TL_) ? GATE * x[idx] : 0.f;
}

// macro[b,t,d] = mean over window [t-7, t+7] clipped to [0,T)
__global__ void pool_kernel(const float* __restrict__ xf, float* __restrict__ mac){
    int idx = blockIdx.x*256 + threadIdx.x;
    int d = idx % D_;
    int t = (idx / D_) % T_;
    int b = idx / (D_*T_);
    int lo = t-7; if (lo < 0) lo = 0;
    int hi = t+7; if (hi > T_-1) hi = T_-1;
    const float* base = xf + ((size_t)b*T_)*D_ + d;
    float s = 0.f;
    for (int u = lo; u <= hi; ++u) s += base[(size_t)u*D_];
    mac[idx] = s / (float)(hi - lo + 1);
}

// ------------------------------------------------------------------
// Tiled fp32 GEMM: C[M,N] (+)= (rowscale?) * act(A[M,K] @ B[K,N] + bias)
#define GF_GELU  1
#define GF_ACCUM 2
#define GF_RS    4

__global__ __launch_bounds__(256) void gemm_kernel(
    const float* __restrict__ A, const float* __restrict__ Bw,
    const float* __restrict__ bias, const float* __restrict__ rs, int rs_stride,
    float* __restrict__ C, int M, int N, int K, int flags)
{
    __shared__ float As[16][65];
    __shared__ float Bs[16][65];
    int tid = threadIdx.x;
    int tx = tid & 15, ty = tid >> 4;
    int m0 = blockIdx.y*64, n0 = blockIdx.x*64;

    int arow = tid >> 2;          // 0..63
    int akq  = (tid & 3) * 4;     // k offset 0,4,8,12
    int bk   = tid >> 4;          // 0..15
    int bn   = (tid & 15) * 4;    // 0..60

    float acc[4][4] = {};

    for (int k0 = 0; k0 < K; k0 += 16){
        const float* Ap = A + (size_t)(m0+arow)*K + k0 + akq;
        As[akq+0][arow] = Ap[0];
        As[akq+1][arow] = Ap[1];
        As[akq+2][arow] = Ap[2];
        As[akq+3][arow] = Ap[3];
        const float* Bp = Bw + (size_t)(k0+bk)*N + n0 + bn;
        if (n0 + bn < N){           // N always multiple of 4
            Bs[bk][bn+0] = Bp[0];
            Bs[bk][bn+1] = Bp[1];
            Bs[bk][bn+2] = Bp[2];
            Bs[bk][bn+3] = Bp[3];
        } else {
            Bs[bk][bn+0] = 0.f; Bs[bk][bn+1] = 0.f;
            Bs[bk][bn+2] = 0.f; Bs[bk][bn+3] = 0.f;
        }
        __syncthreads();
        #pragma unroll
        for (int kk = 0; kk < 16; ++kk){
            float av[4], bv[4];
            #pragma unroll
            for (int i = 0; i < 4; ++i) av[i] = As[kk][ty*4+i];
            #pragma unroll
            for (int j = 0; j < 4; ++j) bv[j] = Bs[kk][tx*4+j];
            #pragma unroll
            for (int i = 0; i < 4; ++i)
                #pragma unroll
                for (int j = 0; j < 4; ++j)
                    acc[i][j] += av[i]*bv[j];
        }
        __syncthreads();
    }

    #pragma unroll
    for (int i = 0; i < 4; ++i){
        int m = m0 + ty*4 + i;
        #pragma unroll
        for (int j = 0; j < 4; ++j){
            int n = n0 + tx*4 + j;
            if (n < N){
                float v = acc[i][j];
                if (bias) v += bias[n];
                if (flags & GF_GELU) v = 0.5f*v*(1.f + erff(v*0.70710678118f));
                if (flags & GF_RS)   v *= rs[(size_t)m*rs_stride];
                size_t ci = (size_t)m*N + n;
                if (flags & GF_ACCUM) C[ci] += v; else C[ci] = v;
            }
        }
    }
}

// ------------------------------------------------------------------
// Flash attention, causal, dh=64, 8 heads. One block per (b, h, 64-row q-tile).
// K-tile = 32 rows so static LDS stays well under 64 KiB.
__global__ __launch_bounds__(256) void flash_kernel(
    const float* __restrict__ Q, const float* __restrict__ Kb,
    const float* __restrict__ Vb, float* __restrict__ O)
{
    int bid = blockIdx.x;
    int qt = bid & 31, h = (bid >> 5) & 7, b = bid >> 8;
    __shared__ float Qs[64][65];   // q rows x dims
    __shared__ float Ks[32][65];   // k rows x dims
    __shared__ float Vs[32][65];
    __shared__ float Ss[64][33];   // q rows x k cols (probabilities)
    __shared__ float mrow[64], lrow[64], arow[64];
    int tid = threadIdx.x;
    int tx = tid & 15, ty = tid >> 4;
    int ty4 = ty*4, tx4 = tx*4, tx2 = tx*2;

    size_t tokbase = (size_t)b*T_ + qt*64;
    {
        int lr = tid >> 2;            // 0..63
        int lc = (tid & 3) * 16;      // 0,16,32,48
        const float* Qp = Q + (tokbase + lr)*D_ + h*64 + lc;
        #pragma unroll
        for (int j = 0; j < 16; ++j) Qs[lr][lc+j] = Qp[j] * 0.125f;  // 1/sqrt(64)
    }
    if (tid < 64){ mrow[tid] = -1e30f; lrow[tid] = 0.f; }
    float o[4][4] = {};

    int nkt = 2*qt + 2;               // 32-row k-tiles covering [0, (qt+1)*64)
    for (int kt = 0; kt < nkt; ++kt){
        __syncthreads();              // protect Ks/Vs/Ss from prior readers
        {
            int kr = tid >> 3;        // 0..31
            int kc = (tid & 7) * 8;   // 0..56
            size_t kbase = (size_t)b*T_ + kt*32;
            const float* Kp = Kb + (kbase + kr)*D_ + h*64 + kc;
            const float* Vp = Vb + (kbase + kr)*D_ + h*64 + kc;
            #pragma unroll
            for (int j = 0; j < 8; ++j){ Ks[kr][kc+j] = Kp[j]; Vs[kr][kc+j] = Vp[j]; }
        }
        __syncthreads();

        // scores: 64 q-rows x 32 k-cols, each thread 4x2
        float s[4][2] = {};
        #pragma unroll 4
        for (int d = 0; d < 64; ++d){
            float qv[4], kv[2];
            #pragma unroll
            for (int i = 0; i < 4; ++i) qv[i] = Qs[ty4+i][d];
            #pragma unroll
            for (int j = 0; j < 2; ++j) kv[j] = Ks[tx2+j][d];
            #pragma unroll
            for (int i = 0; i < 4; ++i)
                #pragma unroll
                for (int j = 0; j < 2; ++j)
                    s[i][j] += qv[i]*kv[j];
        }
        if (kt >= 2*qt){              // tiles overlapping the diagonal
            #pragma unroll
            for (int i = 0; i < 4; ++i)
                #pragma unroll
                for (int j = 0; j < 2; ++j)
                    if (kt*32 + tx2+j > qt*64 + ty4+i) s[i][j] = -1e30f;
        }
        #pragma unroll
        for (int i = 0; i < 4; ++i)
            #pragma unroll
            for (int j = 0; j < 2; ++j)
                Ss[ty4+i][tx2+j] = s[i][j];
        __syncthreads();

        if (tid < 64){
            int r = tid;
            float m_old = mrow[r], mx = m_old;
            for (int c = 0; c < 32; ++c) mx = fmaxf(mx, Ss[r][c]);
            float al = __expf(m_old - mx);
            float sum = 0.f;
            for (int c = 0; c < 32; ++c){
                float p = __expf(Ss[r][c] - mx);
                Ss[r][c] = p; sum += p;
            }
            mrow[r] = mx; lrow[r] = lrow[r]*al + sum; arow[r] = al;
        }
        __syncthreads();

        #pragma unroll
        for (int i = 0; i < 4; ++i){
            float al = arow[ty4+i];
            #pragma unroll
            for (int j = 0; j < 4; ++j) o[i][j] *= al;
        }
        #pragma unroll 4
        for (int k = 0; k < 32; ++k){
            float pv[4], vv[4];
            #pragma unroll
            for (int i = 0; i < 4; ++i) pv[i] = Ss[ty4+i][k];
            #pragma unroll
            for (int j = 0; j < 4; ++j) vv[j] = Vs[k][tx4+j];
            #pragma unroll
            for (int i = 0; i < 4; ++i)
                #pragma unroll
                for (int j = 0; j < 4; ++j)
                    o[i][j] += pv[i]*vv[j];
        }
    }

    #pragma unroll
    for (int i = 0; i < 4; ++i){
        int r = ty4 + i;
        float inv = 1.f / lrow[r];
        #pragma unroll
        for (int j = 0; j < 4; ++j)
            O[(tokbase + r)*D_ + h*64 + tx4 + j] = o[i][j] * inv;
    }
}

// ------------------------------------------------------------------
// x1 = rmsnorm(x + y) * scale   -> fp32 out
__global__ __launch_bounds__(256) void rmsnorm_add_kernel(
    const float* __restrict__ x, const float* __restrict__ y,
    const float* __restrict__ scale, float* __restrict__ out)
{
    int tok = blockIdx.x, tid = threadIdx.x;
    size_t base = (size_t)tok * D_;
    float v0 = x[base+tid]     + y[base+tid];
    float v1 = x[base+tid+256] + y[base+tid+256];
    float ss = v0*v0 + v1*v1;
    for (int off = 32; off; off >>= 1) ss += __shfl_down(ss, off);
    __shared__ float ws[4];
    if ((tid & 63) == 0) ws[tid >> 6] = ss;
    __syncthreads();
    float rstd = rsqrtf((ws[0]+ws[1]+ws[2]+ws[3])*(1.f/512.f) + 1e-6f);
    out[base+tid]     = scale[tid]     * v0 * rstd;
    out[base+tid+256] = scale[tid+256] * v1 * rstd;
}

// out = rmsnorm(x1 + moe) * scale
__global__ __launch_bounds__(256) void final_kernel(
    const float* __restrict__ x1, const float* __restrict__ moe,
    const float* __restrict__ scale, float* __restrict__ out)
{
    int tok = blockIdx.x, tid = threadIdx.x;
    size_t base = (size_t)tok * D_;
    float v0 = x1[base+tid]     + moe[base+tid];
    float v1 = x1[base+tid+256] + moe[base+tid+256];
    float ss = v0*v0 + v1*v1;
    for (int off = 32; off; off >>= 1) ss += __shfl_down(ss, off);
    __shared__ float ws[4];
    if ((tid & 63) == 0) ws[tid >> 6] = ss;
    __syncthreads();
    float rstd = rsqrtf((ws[0]+ws[1]+ws[2]+ws[3])*(1.f/512.f) + 1e-6f);
    out[base+tid]     = scale[tid]     * v0 * rstd;
    out[base+tid+256] = scale[tid+256] * v1 * rstd;
}

// router weights: softmax(x1 @ wr + br) over 4 experts, one wave per token
__global__ __launch_bounds__(256) void router_kernel(
    const float* __restrict__ x1, const float* __restrict__ wr,
    const float* __restrict__ br, float* __restrict__ rout)
{
    int wid = threadIdx.x >> 6, lane = threadIdx.x & 63;
    int tok = blockIdx.x*4 + wid;
    const float* xp = x1 + (size_t)tok*D_;
    float p0=0.f, p1=0.f, p2=0.f, p3=0.f;
    for (int d = lane; d < D_; d += 64){
        float xv = xp[d];
        p0 += xv*wr[d*4+0]; p1 += xv*wr[d*4+1];
        p2 += xv*wr[d*4+2]; p3 += xv*wr[d*4+3];
    }
    for (int off = 32; off; off >>= 1){
        p0 += __shfl_down(p0,off); p1 += __shfl_down(p1,off);
        p2 += __shfl_down(p2,off); p3 += __shfl_down(p3,off);
    }
    if (lane == 0){
        p0 += br[0]; p1 += br[1]; p2 += br[2]; p3 += br[3];
        float mx = fmaxf(fmaxf(p0,p1), fmaxf(p2,p3));
        float e0=__expf(p0-mx), e1=__expf(p1-mx), e2=__expf(p2-mx), e3=__expf(p3-mx);
        float inv = 1.f/(e0+e1+e2+e3);
        rout[tok*4+0]=e0*inv; rout[tok*4+1]=e1*inv;
        rout[tok*4+2]=e2*inv; rout[tok*4+3]=e3*inv;
    }
}

// xg = x1 * sigmoid(g)   (g holds x1@wg + bg), in-place into g
__global__ void xg_kernel(const float* __restrict__ x1, float* __restrict__ g){
    int idx = blockIdx.x*256 + threadIdx.x;
    float t = g[idx];
    g[idx] = x1[idx] / (1.f + __expf(-t));
}

// ------------------------------------------------------------------
extern "C" void kernel_launch(void* const* d_in, const int* in_sizes, int n_in,
                              void* d_out, int out_size, void* d_ws, size_t ws_size,
                              hipStream_t stream)
{
    const float* x    = (const float*)d_in[0];
    const float* mp_w = (const float*)d_in[3];
    const float* mp_b = (const float*)d_in[4];
    const float* fu_w = (const float*)d_in[5];
    const float* fu_b = (const float*)d_in[6];
    const float* wc   = (const float*)d_in[7];
    const float* wk   = (const float*)d_in[8];
    const float* wv   = (const float*)d_in[9];
    const float* wq   = (const float*)d_in[10];
    const float* wo   = (const float*)d_in[11];
    const float* s1   = (const float*)d_in[12];
    const float* s2   = (const float*)d_in[13];
    const float* wr   = (const float*)d_in[14];
    const float* br   = (const float*)d_in[15];
    const float* wg   = (const float*)d_in[16];
    const float* bg   = (const float*)d_in[17];
    const float* w1   = (const float*)d_in[18];
    const float* b1   = (const float*)d_in[19];
    const float* w2   = (const float*)d_in[20];
    const float* b2   = (const float*)d_in[21];

    float* W = (float*)d_ws;
    const size_t BIGF = (size_t)TOK * D_;      // 4,194,304 floats
    float* S0  = W;                            // xf -> K -> xg
    float* S1  = W + 1*BIGF;                   // macro -> xfu -> attn -> moe-acc
    float* S2  = W + 2*BIGF;                   // mf -> V -> x1
    float* S3  = W + 3*BIGF;                   // Q -> attn@wo ; later H (2 BIGF)
    float* Hb  = S3;                           // 8192 x 1024 expert hidden
    float* LAT = W + 5*BIGF;                   // 8192 x 32
    float* ROUT= LAT + (size_t)TOK*32;         // 8192 x 4
    // total: 5*BIGF + 262144 + 32768 floats ~= 85.1 MB

    int ew = (TOK*D_)/256;   // 16384 blocks for elementwise

    auto gemm = [&](const float* A, const float* Bw, const float* bias,
                    const float* rs, int rss, float* C, int M, int N, int K, int flags){
        dim3 g((N+63)/64, (M+63)/64);
        gemm_kernel<<<g, 256, 0, stream>>>(A, Bw, bias, rs, rss, C, M, N, K, flags);
    };

    // 1. temporal gate (collapses to 0.2x) + pooling
    gate_kernel<<<ew, 256, 0, stream>>>(x, S0);                 // S0 = xf
    pool_kernel<<<ew, 256, 0, stream>>>(S0, S1);                // S1 = macro
    // 2. dual-scale fusion
    gemm(S1, mp_w, mp_b, nullptr, 0, S2, TOK, 512, 512, 0);     // S2 = macro_feat
    gemm(S0, fu_w,            fu_b,    nullptr, 0, S1, TOK, 512, 512, 0);        // S1  = xf@fuA + b
    gemm(S2, fu_w + 512*512,  nullptr, nullptr, 0, S1, TOK, 512, 512, GF_ACCUM); // S1 += mf@fuB (xfu)
    // 3. MLA attention
    gemm(S1, wc, nullptr, nullptr, 0, LAT, TOK,  32, 512, 0);   // latent
    gemm(LAT, wk, nullptr, nullptr, 0, S0, TOK, 512,  32, 0);   // K
    gemm(LAT, wv, nullptr, nullptr, 0, S2, TOK, 512,  32, 0);   // V
    gemm(S1, wq, nullptr, nullptr, 0, S3, TOK, 512, 512, 0);    // Q
    flash_kernel<<<1024, 256, 0, stream>>>(S3, S0, S2, S1);     // S1 = attn out (pre-wo)
    gemm(S1, wo, nullptr, nullptr, 0, S3, TOK, 512, 512, 0);    // S3 = attn@wo
    rmsnorm_add_kernel<<<TOK, 256, 0, stream>>>(x, S3, s1, S2); // S2 = x1
    // 4. MoE
    router_kernel<<<TOK/4, 256, 0, stream>>>(S2, wr, br, ROUT);
    gemm(S2, wg, bg, nullptr, 0, S0, TOK, 512, 512, 0);         // S0 = x1@wg + bg
    xg_kernel<<<ew, 256, 0, stream>>>(S2, S0);                  // S0 = xg
    for (int e = 0; e < 4; ++e){
        gemm(S0, w1 + (size_t)e*512*1024, b1 + e*1024, nullptr, 0,
             Hb, TOK, 1024, 512, GF_GELU);                      // H = gelu(xg@w1+b1)
        gemm(Hb, w2 + (size_t)e*1024*512, b2 + e*512, ROUT + e, 4,
             S1, TOK, 512, 1024, (e == 0) ? GF_RS : (GF_RS|GF_ACCUM)); // S1 (+)= w_e*(H@w2+b2)
    }
    // 5. final residual rmsnorm -> fp32 out
    final_kernel<<<TOK, 256, 0, stream>>>(S2, S1, s2, (float*)d_out);
}

// Round 3
// 880.462 us; speedup vs baseline: 3.4144x; 3.4144x over previous
//
#include <hip/hip_runtime.h>
#include <math.h>

#define B_   4
#define T_   2048
#define D_   512
#define TOK  (B_*T_)      // 8192 tokens
#define TL_  2045         // N_BLOCKS*(T//N_BLOCKS) = 5*409
#define GATE 0.2f         // softmax(...).mean(-1) over same axis == 1/5

typedef unsigned short u16;
typedef __attribute__((ext_vector_type(8))) short short8;   // 8 bf16 = 4 VGPRs
typedef __attribute__((ext_vector_type(4))) float f32x4;

static __device__ __forceinline__ u16 f2u(float f){      // fp32 -> bf16 (RNE)
    union { float f; unsigned u; } a; a.f = f;
    unsigned r = a.u + 0x7fffu + ((a.u >> 16) & 1u);
    return (u16)(r >> 16);
}
static __device__ __forceinline__ float u2f(u16 u){
    union { unsigned u; float f; } a; a.u = ((unsigned)u) << 16;
    return a.f;
}
static __device__ __forceinline__ f32x4 mfma16(short8 a, short8 b, f32x4 c){
    return __builtin_amdgcn_mfma_f32_16x16x32_bf16(a, b, c, 0, 0, 0);
}
static __device__ __forceinline__ void glds16(const u16* g, u16* l){
    __builtin_amdgcn_global_load_lds((const __attribute__((address_space(1))) void*)g,
                                     (__attribute__((address_space(3))) void*)l, 16, 0, 0);
}

// ------------------------------------------------------------------
// XFcat[:, 0:512] = bf16(0.2 * x masked at t>=TL)
__global__ void gate_kernel(const float* __restrict__ x, u16* __restrict__ xfcat){
    int idx = blockIdx.x*256 + threadIdx.x;
    int d = idx & 511; int tok = idx >> 9; int t = tok & 2047;
    float v = (t < TL_) ? GATE * x[idx] : 0.f;
    xfcat[(size_t)tok*1024 + d] = f2u(v);
}

// MACRO = bf16(avgpool15(xf)); xf = 0.2*x masked, denominator = clipped window size
__global__ void pool_kernel(const float* __restrict__ x, u16* __restrict__ mac){
    int idx = blockIdx.x*256 + threadIdx.x;
    int d = idx & 511; int tok = idx >> 9; int t = tok & 2047; int b = tok >> 11;
    int lo = t-7; if (lo < 0) lo = 0;
    int hi = t+7; if (hi > 2047) hi = 2047;
    int he = hi; if (he > TL_-1) he = TL_-1;    // values at t>=TL are zero
    const float* base = x + ((size_t)b*2048)*512 + d;
    float s = 0.f;
    for (int u = lo; u <= he; ++u) s += base[(size_t)u*512];
    mac[idx] = f2u(GATE * s / (float)(hi - lo + 1));
}

// transpose+convert: in fp32 [K][N] -> out bf16 [N][K]
__global__ __launch_bounds__(256) void tconv_kernel(const float* __restrict__ in,
                                                    u16* __restrict__ out, int K, int N){
    __shared__ float t[32][33];
    int k0 = blockIdx.y*32, n0 = blockIdx.x*32;
    int tx = threadIdx.x & 31, ty = threadIdx.x >> 5;   // ty 0..7
    #pragma unroll
    for (int i = 0; i < 32; i += 8)
        t[ty+i][tx] = in[(size_t)(k0+ty+i)*N + n0+tx];
    __syncthreads();
    #pragma unroll
    for (int i = 0; i < 32; i += 8)
        out[(size_t)(n0+ty+i)*K + k0+tx] = f2u(t[tx][ty+i]);
}

// small fp32 GEMM (for Wck = wc@wk, Wcv = wc@wv): C[M,N] = A[M,K]@B[K,N]
__global__ __launch_bounds__(256) void sgemm_kernel(const float* __restrict__ A,
    const float* __restrict__ B, float* __restrict__ C, int M, int N, int K){
    __shared__ float As[16][65];
    __shared__ float Bs[16][65];
    int tid = threadIdx.x;
    int tx = tid & 15, ty = tid >> 4;
    int m0 = blockIdx.y*64, n0 = blockIdx.x*64;
    int arow = tid >> 2, akq = (tid & 3) * 4;
    int bk = tid >> 4, bn = (tid & 15) * 4;
    float acc[4][4] = {};
    for (int k0 = 0; k0 < K; k0 += 16){
        const float* Ap = A + (size_t)(m0+arow)*K + k0 + akq;
        As[akq+0][arow]=Ap[0]; As[akq+1][arow]=Ap[1];
        As[akq+2][arow]=Ap[2]; As[akq+3][arow]=Ap[3];
        const float* Bp = B + (size_t)(k0+bk)*N + n0 + bn;
        Bs[bk][bn+0]=Bp[0]; Bs[bk][bn+1]=Bp[1];
        Bs[bk][bn+2]=Bp[2]; Bs[bk][bn+3]=Bp[3];
        __syncthreads();
        #pragma unroll
        for (int kk = 0; kk < 16; ++kk){
            float av[4], bv[4];
            #pragma unroll
            for (int i=0;i<4;++i) av[i]=As[kk][ty*4+i];
            #pragma unroll
            for (int j=0;j<4;++j) bv[j]=Bs[kk][tx*4+j];
            #pragma unroll
            for (int i=0;i<4;++i)
                #pragma unroll
                for (int j=0;j<4;++j) acc[i][j] += av[i]*bv[j];
        }
        __syncthreads();
    }
    #pragma unroll
    for (int i=0;i<4;++i)
        #pragma unroll
        for (int j=0;j<4;++j)
            C[(size_t)(m0+ty*4+i)*N + n0+tx*4+j] = acc[i][j];
}

// ------------------------------------------------------------------
// bf16 MFMA GEMM: C[M,N] = op(A[M,K] @ Bt[N,K]^T + bias)
// 128x128 tile, BK=64, 4 waves (2x2), each wave 64x64 (4x4 MFMA tiles).
// LDS XOR-swizzle: chunk (row, g) stored at slot g^(row&7) -> conflict-free b128.
#define GF_GELU   1
#define GF_ACCUM  2
#define GF_RS     4
#define GF_GLU    8
#define GF_F32OUT 16

__global__ __launch_bounds__(256) void mgemm_kernel(
    const u16* __restrict__ A, const u16* __restrict__ Bt,
    const float* __restrict__ bias, const float* __restrict__ rs,
    const u16* __restrict__ glu, void* __restrict__ Cp,
    int M, int N, int K, int ldc, int flags)
{
    __shared__ u16 As[128*64];
    __shared__ u16 Bs[128*64];
    int tid = threadIdx.x;
    int wave = tid >> 6, lane = tid & 63;
    int n16 = lane & 15, quad = lane >> 4;
    int m0 = blockIdx.y * 128, n0 = blockIdx.x * 128;
    int wr = (wave >> 1) * 64, wc = (wave & 1) * 64;

    f32x4 acc[4][4] = {};

    for (int k0 = 0; k0 < K; k0 += 64){
        #pragma unroll
        for (int i = 0; i < 4; ++i){
            int s = i*256 + tid;
            int row = s >> 3, gp = s & 7;
            int g = gp ^ (row & 7);
            glds16(A  + (size_t)(m0+row)*K + k0 + g*8, As + (size_t)s*8);
            glds16(Bt + (size_t)(n0+row)*K + k0 + g*8, Bs + (size_t)s*8);
        }
        __syncthreads();
        #pragma unroll
        for (int ks = 0; ks < 2; ++ks){
            short8 af[4], bf[4];
            #pragma unroll
            for (int mi = 0; mi < 4; ++mi){
                int row = wr + mi*16 + n16;
                int g = (ks*4 + quad) ^ (row & 7);
                af[mi] = *(const short8*)&As[row*64 + g*8];
            }
            #pragma unroll
            for (int ni = 0; ni < 4; ++ni){
                int row = wc + ni*16 + n16;
                int g = (ks*4 + quad) ^ (row & 7);
                bf[ni] = *(const short8*)&Bs[row*64 + g*8];
            }
            #pragma unroll
            for (int mi = 0; mi < 4; ++mi)
                #pragma unroll
                for (int ni = 0; ni < 4; ++ni)
                    acc[mi][ni] = mfma16(af[mi], bf[ni], acc[mi][ni]);
        }
        __syncthreads();
    }

    #pragma unroll
    for (int mi = 0; mi < 4; ++mi){
        #pragma unroll
        for (int reg = 0; reg < 4; ++reg){
            int row = m0 + wr + mi*16 + quad*4 + reg;
            float rsv = (flags & GF_RS) ? rs[(size_t)row*4] : 1.f;
            #pragma unroll
            for (int ni = 0; ni < 4; ++ni){
                int col = n0 + wc + ni*16 + n16;
                float v = acc[mi][ni][reg];
                if (bias) v += bias[col];
                if (flags & GF_GELU) v = 0.5f*v*(1.f + erff(v*0.70710678118f));
                if (flags & GF_GLU)  v = u2f(glu[(size_t)row*512 + col]) / (1.f + __expf(-v));
                if (flags & GF_RS)   v *= rsv;
                size_t ci = (size_t)row*ldc + col;
                if (flags & GF_ACCUM)       ((float*)Cp)[ci] += v;
                else if (flags & GF_F32OUT) ((float*)Cp)[ci]  = v;
                else                        ((u16*)Cp)[ci]    = f2u(v);
            }
        }
    }
}

// ------------------------------------------------------------------
// MFMA flash attention (bf16), causal, dh=64, 8 heads.
// Block = 256 thr (4 waves), Q-tile 64 (wave w owns rows w*16..+16), K-tile 64.
__global__ __launch_bounds__(256) void flash_kernel(
    const u16* __restrict__ Q, const u16* __restrict__ K,
    const u16* __restrict__ V, u16* __restrict__ O)
{
    int bid = blockIdx.x;
    int qt = 31 - (bid & 31);          // heavy tiles dispatch first
    int h = (bid >> 5) & 7, b = bid >> 8;
    __shared__ u16 Qs[64*72];          // [qrow][d], pad 8 -> 2-way max
    __shared__ u16 Ks[64*72];          // [krow][d]
    __shared__ u16 Vt[64*72];          // [d][krow]  (V transposed)
    __shared__ u16 Ps[4][16*72];       // per-wave P [row][kcol]
    int tid = threadIdx.x;
    int wave = tid >> 6, lane = tid & 63;
    int n16 = lane & 15, quad = lane >> 4;
    size_t tok0 = (size_t)b*2048 + qt*64;

    {   // stage Q
        int r = tid >> 2, c0 = (tid & 3) * 16;
        const uint4* gp = (const uint4*)(Q + (tok0 + r)*512 + h*64 + c0);
        uint4 v0 = gp[0], v1 = gp[1];
        *(uint4*)&Qs[r*72 + c0]     = v0;
        *(uint4*)&Qs[r*72 + c0 + 8] = v1;
    }
    float m_st[4], l_st[4];
    #pragma unroll
    for (int r = 0; r < 4; ++r){ m_st[r] = -3.0e38f; l_st[r] = 0.f; }
    f32x4 ov[4] = {};

    for (int kt = 0; kt <= qt; ++kt){
        __syncthreads();               // protect Ks/Vt reuse
        {
            size_t ktok = (size_t)b*2048 + kt*64;
            int r = tid >> 2, c0 = (tid & 3) * 16;
            const uint4* kp = (const uint4*)(K + (ktok + r)*512 + h*64 + c0);
            uint4 kv0 = kp[0], kv1 = kp[1];
            *(uint4*)&Ks[r*72 + c0]     = kv0;
            *(uint4*)&Ks[r*72 + c0 + 8] = kv1;
            const u16* vp = V + (ktok + r)*512 + h*64 + c0;
            u16 vv[16];
            *(uint4*)&vv[0] = *(const uint4*)vp;
            *(uint4*)&vv[8] = *(const uint4*)(vp + 8);
            #pragma unroll
            for (int j = 0; j < 16; ++j){
                int jj = (j + r) & 15;             // stagger banks
                Vt[(c0 + jj)*72 + r] = vv[jj];
            }
        }
        __syncthreads();

        // S = Q K^T * 0.125
        short8 aq[2];
        #pragma unroll
        for (int ks = 0; ks < 2; ++ks)
            aq[ks] = *(const short8*)&Qs[(wave*16 + n16)*72 + ks*32 + quad*8];
        f32x4 s[4];
        #pragma unroll
        for (int ct = 0; ct < 4; ++ct){
            f32x4 a = {};
            #pragma unroll
            for (int ks = 0; ks < 2; ++ks){
                short8 bk = *(const short8*)&Ks[(ct*16 + n16)*72 + ks*32 + quad*8];
                a = mfma16(aq[ks], bk, a);
            }
            s[ct] = a * 0.125f;
        }
        if (kt == qt){                 // causal mask on diagonal tile
            int rowbase = wave*16 + quad*4;
            #pragma unroll
            for (int ct = 0; ct < 4; ++ct){
                int col = ct*16 + n16;
                #pragma unroll
                for (int r = 0; r < 4; ++r)
                    if (col > rowbase + r) s[ct][r] = -3.0e38f;
            }
        }
        // online softmax (rows live in 16-lane quad groups)
        float alpha[4];
        #pragma unroll
        for (int r = 0; r < 4; ++r){
            float mx = fmaxf(fmaxf(s[0][r], s[1][r]), fmaxf(s[2][r], s[3][r]));
            #pragma unroll
            for (int off = 1; off < 16; off <<= 1)
                mx = fmaxf(mx, __shfl_xor(mx, off));
            float mn = fmaxf(m_st[r], mx);
            alpha[r] = __expf(m_st[r] - mn);
            m_st[r] = mn;
            float sum = 0.f;
            #pragma unroll
            for (int ct = 0; ct < 4; ++ct){
                float p = __expf(s[ct][r] - mn);
                s[ct][r] = p;
                sum += p;
            }
            #pragma unroll
            for (int off = 1; off < 16; off <<= 1)
                sum += __shfl_xor(sum, off);
            l_st[r] = l_st[r]*alpha[r] + sum;
        }
        // P -> per-wave LDS (row-major for A-frag reads)
        u16* pw = &Ps[wave][0];
        #pragma unroll
        for (int ct = 0; ct < 4; ++ct)
            #pragma unroll
            for (int r = 0; r < 4; ++r)
                pw[(quad*4 + r)*72 + ct*16 + n16] = f2u(s[ct][r]);
        #pragma unroll
        for (int dt = 0; dt < 4; ++dt)
            #pragma unroll
            for (int r = 0; r < 4; ++r)
                ov[dt][r] *= alpha[r];
        // O += P V
        short8 ap[2];
        #pragma unroll
        for (int ks = 0; ks < 2; ++ks)
            ap[ks] = *(const short8*)&pw[n16*72 + ks*32 + quad*8];
        #pragma unroll
        for (int dt = 0; dt < 4; ++dt){
            #pragma unroll
            for (int ks = 0; ks < 2; ++ks){
                short8 bv = *(const short8*)&Vt[(dt*16 + n16)*72 + ks*32 + quad*8];
                ov[dt] = mfma16(ap[ks], bv, ov[dt]);
            }
        }
    }
    #pragma unroll
    for (int r = 0; r < 4; ++r){
        float inv = 1.f / l_st[r];
        size_t row = tok0 + wave*16 + quad*4 + r;
        #pragma unroll
        for (int dt = 0; dt < 4; ++dt)
            O[row*512 + h*64 + dt*16 + n16] = f2u(ov[dt][r] * inv);
    }
}

// ------------------------------------------------------------------
// x1h = bf16( rmsnorm(x + y_bf16) * scale )
__global__ __launch_bounds__(256) void rmsnorm_kernel(
    const float* __restrict__ x, const u16* __restrict__ y,
    const float* __restrict__ scale, u16* __restrict__ out)
{
    int tok = blockIdx.x, tid = threadIdx.x;
    size_t base = (size_t)tok * 512;
    float v0 = x[base+tid]     + u2f(y[base+tid]);
    float v1 = x[base+tid+256] + u2f(y[base+tid+256]);
    float ss = v0*v0 + v1*v1;
    for (int off = 32; off; off >>= 1) ss += __shfl_down(ss, off);
    __shared__ float ws[4];
    if ((tid & 63) == 0) ws[tid >> 6] = ss;
    __syncthreads();
    float rstd = rsqrtf((ws[0]+ws[1]+ws[2]+ws[3])*(1.f/512.f) + 1e-6f);
    out[base+tid]     = f2u(scale[tid]     * v0 * rstd);
    out[base+tid+256] = f2u(scale[tid+256] * v1 * rstd);
}

// out_fp32 = rmsnorm(x1h + moe) * scale
__global__ __launch_bounds__(256) void final_kernel(
    const u16* __restrict__ x1, const float* __restrict__ moe,
    const float* __restrict__ scale, float* __restrict__ out)
{
    int tok = blockIdx.x, tid = threadIdx.x;
    size_t base = (size_t)tok * 512;
    float v0 = u2f(x1[base+tid])     + moe[base+tid];
    float v1 = u2f(x1[base+tid+256]) + moe[base+tid+256];
    float ss = v0*v0 + v1*v1;
    for (int off = 32; off; off >>= 1) ss += __shfl_down(ss, off);
    __shared__ float ws[4];
    if ((tid & 63) == 0) ws[tid >> 6] = ss;
    __syncthreads();
    float rstd = rsqrtf((ws[0]+ws[1]+ws[2]+ws[3])*(1.f/512.f) + 1e-6f);
    out[base+tid]     = scale[tid]     * v0 * rstd;
    out[base+tid+256] = scale[tid+256] * v1 * rstd;
}

// router: softmax(x1h @ wr + br), one wave per token
__global__ __launch_bounds__(256) void router_kernel(
    const u16* __restrict__ x1, const float* __restrict__ wr,
    const float* __restrict__ br, float* __restrict__ rout)
{
    int wid = threadIdx.x >> 6, lane = threadIdx.x & 63;
    int tok = blockIdx.x*4 + wid;
    const u16* xp = x1 + (size_t)tok*512;
    float p0=0.f, p1=0.f, p2=0.f, p3=0.f;
    for (int d = lane; d < 512; d += 64){
        float xv = u2f(xp[d]);
        p0 += xv*wr[d*4+0]; p1 += xv*wr[d*4+1];
        p2 += xv*wr[d*4+2]; p3 += xv*wr[d*4+3];
    }
    for (int off = 32; off; off >>= 1){
        p0 += __shfl_down(p0,off); p1 += __shfl_down(p1,off);
        p2 += __shfl_down(p2,off); p3 += __shfl_down(p3,off);
    }
    if (lane == 0){
        p0 += br[0]; p1 += br[1]; p2 += br[2]; p3 += br[3];
        float mx = fmaxf(fmaxf(p0,p1), fmaxf(p2,p3));
        float e0=__expf(p0-mx), e1=__expf(p1-mx), e2=__expf(p2-mx), e3=__expf(p3-mx);
        float inv = 1.f/(e0+e1+e2+e3);
        rout[tok*4+0]=e0*inv; rout[tok*4+1]=e1*inv;
        rout[tok*4+2]=e2*inv; rout[tok*4+3]=e3*inv;
    }
}

// ------------------------------------------------------------------
extern "C" void kernel_launch(void* const* d_in, const int* in_sizes, int n_in,
                              void* d_out, int out_size, void* d_ws, size_t ws_size,
                              hipStream_t stream)
{
    const float* x    = (const float*)d_in[0];
    const float* mp_w = (const float*)d_in[3];
    const float* mp_b = (const float*)d_in[4];
    const float* fu_w = (const float*)d_in[5];
    const float* fu_b = (const float*)d_in[6];
    const float* wc   = (const float*)d_in[7];
    const float* wk   = (const float*)d_in[8];
    const float* wv   = (const float*)d_in[9];
    const float* wq   = (const float*)d_in[10];
    const float* wo   = (const float*)d_in[11];
    const float* s1   = (const float*)d_in[12];
    const float* s2   = (const float*)d_in[13];
    const float* wr   = (const float*)d_in[14];
    const float* br   = (const float*)d_in[15];
    const float* wg   = (const float*)d_in[16];
    const float* bg   = (const float*)d_in[17];
    const float* w1   = (const float*)d_in[18];
    const float* b1   = (const float*)d_in[19];
    const float* w2   = (const float*)d_in[20];
    const float* b2   = (const float*)d_in[21];

    char* wsb = (char*)d_ws;
    const size_t MB = 1024*1024;
    // weights region (persistent): 12 MB + ROUT
    size_t off = 0;
    u16* mp_wT = (u16*)(wsb + off); off += 512*512*2;
    u16* fu_wT = (u16*)(wsb + off); off += 512*1024*2;
    u16* wqT   = (u16*)(wsb + off); off += 512*512*2;
    u16* woT   = (u16*)(wsb + off); off += 512*512*2;
    u16* wgT   = (u16*)(wsb + off); off += 512*512*2;
    u16* WckT  = (u16*)(wsb + off); off += 512*512*2;
    u16* WcvT  = (u16*)(wsb + off); off += 512*512*2;
    u16* w1T   = (u16*)(wsb + off); off += (size_t)4*1024*512*2;
    u16* w2T   = (u16*)(wsb + off); off += (size_t)4*512*1024*2;
    float* ROUT= (float*)(wsb + off); off += TOK*4*4;
    // big slots
    char* A0v = wsb + 13*MB;     // 16 MB: WckF/WcvF(pre) -> XFcat -> MOE
    char* A1v = wsb + 29*MB;     // 16 MB: MACRO+XFU -> Hb
    char* A2v = wsb + 45*MB;     // 24 MB: Qb,Kb,Vb -> S3,x1h,XG
    char* A3v = wsb + 69*MB;     //  8 MB: ATT          (total 77 MB)
    float* WckF = (float*)A0v;
    float* WcvF = (float*)(A0v + 1*MB);
    u16* XFcat = (u16*)A0v;   float* MOE = (float*)A0v;
    u16* MACRO = (u16*)A1v;   u16* XFU = (u16*)(A1v + 8*MB);   u16* Hb = (u16*)A1v;
    u16* Qb = (u16*)A2v;      u16* Kb = (u16*)(A2v + 8*MB);    u16* Vb = (u16*)(A2v + 16*MB);
    u16* S3 = (u16*)A2v;      u16* x1h = (u16*)(A2v + 8*MB);   u16* XG = (u16*)(A2v + 16*MB);
    u16* ATT = (u16*)A3v;

    auto mg = [&](const u16* A, const u16* Bt, const float* bias, const float* rs,
                  const u16* glu, void* C, int M, int N, int K, int ldc, int flags){
        dim3 g(N/128, M/128);
        mgemm_kernel<<<g, 256, 0, stream>>>(A, Bt, bias, rs, glu, C, M, N, K, ldc, flags);
    };
    auto tc = [&](const float* in, u16* out, int K, int N){
        tconv_kernel<<<dim3(N/32, K/32), 256, 0, stream>>>(in, out, K, N);
    };

    // ---- pre-pass: fold wc@wk / wc@wv, transpose+bf16 all weights
    sgemm_kernel<<<dim3(8,8), 256, 0, stream>>>(wc, wk, WckF, 512, 512, 32);
    sgemm_kernel<<<dim3(8,8), 256, 0, stream>>>(wc, wv, WcvF, 512, 512, 32);
    tc(mp_w, mp_wT, 512, 512);
    tc(fu_w, fu_wT, 1024, 512);
    tc(wq, wqT, 512, 512);
    tc(wo, woT, 512, 512);
    tc(wg, wgT, 512, 512);
    tc(WckF, WckT, 512, 512);
    tc(WcvF, WcvT, 512, 512);
    for (int e = 0; e < 4; ++e){
        tc(w1 + (size_t)e*512*1024, w1T + (size_t)e*1024*512, 512, 1024);
        tc(w2 + (size_t)e*1024*512, w2T + (size_t)e*512*1024, 1024, 512);
    }

    // ---- main pipeline
    gate_kernel<<<TOK*512/256, 256, 0, stream>>>(x, XFcat);
    pool_kernel<<<TOK*512/256, 256, 0, stream>>>(x, MACRO);
    mg(MACRO, mp_wT, mp_b, 0, 0, XFcat + 512, TOK, 512, 512, 1024, 0);   // macro_feat
    mg(XFcat, fu_wT, fu_b, 0, 0, XFU, TOK, 512, 1024, 512, 0);           // xfu
    mg(XFU, WckT, 0, 0, 0, Kb, TOK, 512, 512, 512, 0);                   // K = xfu@(wc@wk)
    mg(XFU, WcvT, 0, 0, 0, Vb, TOK, 512, 512, 512, 0);                   // V
    mg(XFU, wqT,  0, 0, 0, Qb, TOK, 512, 512, 512, 0);                   // Q
    flash_kernel<<<1024, 256, 0, stream>>>(Qb, Kb, Vb, ATT);
    mg(ATT, woT, 0, 0, 0, S3, TOK, 512, 512, 512, 0);                    // attn @ wo
    rmsnorm_kernel<<<TOK, 256, 0, stream>>>(x, S3, s1, x1h);             // x1
    router_kernel<<<TOK/4, 256, 0, stream>>>(x1h, wr, br, ROUT);
    mg(x1h, wgT, bg, 0, x1h, XG, TOK, 512, 512, 512, GF_GLU);            // xg = x1*sig(x1@wg+bg)
    for (int e = 0; e < 4; ++e){
        mg(XG, w1T + (size_t)e*1024*512, b1 + e*1024, 0, 0,
           Hb, TOK, 1024, 512, 1024, GF_GELU);                           // H = gelu(xg@w1+b1)
        mg(Hb, w2T + (size_t)e*512*1024, b2 + e*512, ROUT + e, 0,
           MOE, TOK, 512, 1024, 512, GF_RS | (e ? GF_ACCUM : GF_F32OUT)); // MOE (+)= w_e*(H@w2+b2)
    }
    final_kernel<<<TOK, 256, 0, stream>>>(x1h, MOE, s2, (float*)d_out);
}

// Round 4
// 696.952 us; speedup vs baseline: 4.3135x; 1.2633x over previous
//
#include <hip/hip_runtime.h>
#include <math.h>

#define B_   4
#define T_   2048
#define D_   512
#define TOK  (B_*T_)      // 8192 tokens
#define TL_  2045         // N_BLOCKS*(T//N_BLOCKS) = 5*409
#define GATE 0.2f         // softmax(...).mean(-1) over same axis == 1/5

typedef unsigned short u16;
typedef __attribute__((ext_vector_type(8))) short short8;   // 8 bf16 = 4 VGPRs
typedef __attribute__((ext_vector_type(4))) float f32x4;

static __device__ __forceinline__ u16 f2u(float f){      // fp32 -> bf16 (RNE)
    union { float f; unsigned u; } a; a.f = f;
    unsigned r = a.u + 0x7fffu + ((a.u >> 16) & 1u);
    return (u16)(r >> 16);
}
static __device__ __forceinline__ float u2f(u16 u){
    union { unsigned u; float f; } a; a.u = ((unsigned)u) << 16;
    return a.f;
}
static __device__ __forceinline__ f32x4 mfma16(short8 a, short8 b, f32x4 c){
    return __builtin_amdgcn_mfma_f32_16x16x32_bf16(a, b, c, 0, 0, 0);
}
static __device__ __forceinline__ void glds16(const u16* g, u16* l){
    __builtin_amdgcn_global_load_lds((const __attribute__((address_space(1))) void*)g,
                                     (__attribute__((address_space(3))) void*)l, 16, 0, 0);
}

// ------------------------------------------------------------------
// gate + pool fused: XFcat[:,0:512]=bf16(0.2*x masked), XFcat[:,512:]=bf16(pool)
// thread handles 16 consecutive t for one (b,d): sliding window via prefix sums
__global__ __launch_bounds__(256) void gatepool_kernel(
    const float* __restrict__ x, u16* __restrict__ xfcat)
{
    int idx = blockIdx.x*256 + threadIdx.x;
    int d = idx & 511, g = idx >> 9;
    int b = g >> 7, t0 = (g & 127) << 4;
    const float* xp = x + ((size_t)b*2048)*512 + d;
    float v[30];
    #pragma unroll
    for (int j = 0; j < 30; ++j){
        int u = t0 - 7 + j;
        v[j] = (u >= 0 && u < TL_) ? xp[(size_t)u*512] : 0.f;
    }
    float p[31]; p[0] = 0.f;
    #pragma unroll
    for (int j = 0; j < 30; ++j) p[j+1] = p[j] + v[j];
    u16* xc = xfcat + ((size_t)(b*2048 + t0))*1024 + d;
    #pragma unroll
    for (int i = 0; i < 16; ++i){
        int t = t0 + i;
        float sum = p[i+15] - p[i];                 // u in [t-7, t+7]
        int lo = t-7; if (lo < 0) lo = 0;
        int hi = t+7; if (hi > 2047) hi = 2047;
        xc[(size_t)i*1024]       = f2u((t < TL_) ? GATE*v[i+7] : 0.f);
        xc[(size_t)i*1024 + 512] = f2u(GATE * sum / (float)(hi - lo + 1));
    }
}

// ------------------------------------------------------------------
// batched transpose+convert: src fp32 [K,N] -> dst bf16 rows n: dst[n*ldout+coloff+k]
struct TJob { const float* src; u16* dst; int K, N, ldout, coloff, tiles; };
struct TJobs { TJob j[12]; int n; };

__global__ __launch_bounds__(256) void tconv_all_kernel(TJobs JJ){
    __shared__ float t[32][33];
    int idx = blockIdx.x;
    int jb = 0;
    while (jb < JJ.n - 1 && idx >= JJ.j[jb].tiles){ idx -= JJ.j[jb].tiles; ++jb; }
    TJob J = JJ.j[jb];
    int tX = J.N >> 5;
    int k0 = (idx / tX) * 32, n0 = (idx % tX) * 32;
    int tx = threadIdx.x & 31, ty = threadIdx.x >> 5;
    #pragma unroll
    for (int i = 0; i < 32; i += 8)
        t[ty+i][tx] = J.src[(size_t)(k0+ty+i)*J.N + n0+tx];
    __syncthreads();
    #pragma unroll
    for (int i = 0; i < 32; i += 8)
        J.dst[(size_t)(n0+ty+i)*J.ldout + J.coloff + k0+tx] = f2u(t[tx][ty+i]);
}

// fp32 -> bf16 plain convert
__global__ void convert_kernel(const float* __restrict__ in, u16* __restrict__ out){
    int idx = blockIdx.x*256 + threadIdx.x;
    out[idx] = f2u(in[idx]);
}

// fubias[n] = fu_b[n] + sum_d mp_b[d] * fu_w[512+d][n]
__global__ __launch_bounds__(256) void biasfold_kernel(
    const float* __restrict__ fu_b, const float* __restrict__ mp_b,
    const float* __restrict__ fu_w, float* __restrict__ out)
{
    int n = blockIdx.x, tid = threadIdx.x;
    float s = mp_b[tid]*fu_w[(size_t)(512+tid)*512 + n]
            + mp_b[tid+256]*fu_w[(size_t)(768+tid)*512 + n];
    for (int off = 32; off; off >>= 1) s += __shfl_down(s, off);
    __shared__ float ws[4];
    if ((tid & 63) == 0) ws[tid >> 6] = s;
    __syncthreads();
    if (tid == 0) out[n] = fu_b[n] + ws[0]+ws[1]+ws[2]+ws[3];
}

// small fp32 GEMM writing bf16 TRANSPOSED: dstT[n*ldT + m] = (A@B)[m][n]
__global__ __launch_bounds__(256) void sgemm_kernel(const float* __restrict__ A,
    const float* __restrict__ B, u16* __restrict__ dstT, int ldT, int K){
    __shared__ float As[16][65];
    __shared__ float Bs[16][65];
    int tid = threadIdx.x;
    int tx = tid & 15, ty = tid >> 4;
    int m0 = blockIdx.y*64, n0 = blockIdx.x*64;
    int arow = tid >> 2, akq = (tid & 3) * 4;
    int bk = tid >> 4, bn = (tid & 15) * 4;
    float acc[4][4] = {};
    for (int k0 = 0; k0 < K; k0 += 16){
        const float* Ap = A + (size_t)(m0+arow)*K + k0 + akq;
        As[akq+0][arow]=Ap[0]; As[akq+1][arow]=Ap[1];
        As[akq+2][arow]=Ap[2]; As[akq+3][arow]=Ap[3];
        const float* Bp = B + (size_t)(k0+bk)*512 + n0 + bn;
        Bs[bk][bn+0]=Bp[0]; Bs[bk][bn+1]=Bp[1];
        Bs[bk][bn+2]=Bp[2]; Bs[bk][bn+3]=Bp[3];
        __syncthreads();
        #pragma unroll
        for (int kk = 0; kk < 16; ++kk){
            float av[4], bv[4];
            #pragma unroll
            for (int i=0;i<4;++i) av[i]=As[kk][ty*4+i];
            #pragma unroll
            for (int j=0;j<4;++j) bv[j]=Bs[kk][tx*4+j];
            #pragma unroll
            for (int i=0;i<4;++i)
                #pragma unroll
                for (int j=0;j<4;++j) acc[i][j] += av[i]*bv[j];
        }
        __syncthreads();
    }
    #pragma unroll
    for (int i=0;i<4;++i)
        #pragma unroll
        for (int j=0;j<4;++j)
            dstT[(size_t)(n0+tx*4+j)*ldT + m0+ty*4+i] = f2u(acc[i][j]);
}

// ------------------------------------------------------------------
// bf16 MFMA GEMM: C[M,N] = op(A[M,K] @ Bt[N,K]^T + bias), 128x128 tile, BK=64.
#define GF_GELU   1
#define GF_ACCUM  2
#define GF_RSCOL  4
#define GF_GLU    8
#define GF_F32OUT 16
#define GF_TRANS  32

__global__ __launch_bounds__(256) void mgemm_kernel(
    const u16* __restrict__ A, int lda, const u16* __restrict__ Bt, int ldb,
    const float* __restrict__ bias, const float* __restrict__ rs,
    const u16* __restrict__ glu, void* __restrict__ Cp, int ldc,
    int K, int flags)
{
    __shared__ u16 As[128*64];
    __shared__ u16 Bs[128*64];
    int tid = threadIdx.x;
    int wave = tid >> 6, lane = tid & 63;
    int n16 = lane & 15, quad = lane >> 4;
    int m0 = blockIdx.y * 128, n0 = blockIdx.x * 128;
    int wr = (wave >> 1) * 64, wc = (wave & 1) * 64;

    f32x4 acc[4][4] = {};

    for (int k0 = 0; k0 < K; k0 += 64){
        #pragma unroll
        for (int i = 0; i < 4; ++i){
            int s = i*256 + tid;
            int row = s >> 3, gp = s & 7;
            int g = gp ^ (row & 7);
            glds16(A  + (size_t)(m0+row)*lda + k0 + g*8, As + (size_t)s*8);
            glds16(Bt + (size_t)(n0+row)*ldb + k0 + g*8, Bs + (size_t)s*8);
        }
        __syncthreads();
        #pragma unroll
        for (int ks = 0; ks < 2; ++ks){
            short8 af[4], bf[4];
            #pragma unroll
            for (int mi = 0; mi < 4; ++mi){
                int row = wr + mi*16 + n16;
                int g = (ks*4 + quad) ^ (row & 7);
                af[mi] = *(const short8*)&As[row*64 + g*8];
            }
            #pragma unroll
            for (int ni = 0; ni < 4; ++ni){
                int row = wc + ni*16 + n16;
                int g = (ks*4 + quad) ^ (row & 7);
                bf[ni] = *(const short8*)&Bs[row*64 + g*8];
            }
            #pragma unroll
            for (int mi = 0; mi < 4; ++mi)
                #pragma unroll
                for (int ni = 0; ni < 4; ++ni)
                    acc[mi][ni] = mfma16(af[mi], bf[ni], acc[mi][ni]);
        }
        __syncthreads();
    }

    if (flags & GF_TRANS){
        // C^T store (for V^T): Cp[col*ldc + row], pack 4 consecutive rows (8B)
        #pragma unroll
        for (int mi = 0; mi < 4; ++mi){
            int row0 = m0 + wr + mi*16 + quad*4;
            #pragma unroll
            for (int ni = 0; ni < 4; ++ni){
                int col = n0 + wc + ni*16 + n16;
                ushort4 h4;
                h4.x = f2u(acc[mi][ni][0]); h4.y = f2u(acc[mi][ni][1]);
                h4.z = f2u(acc[mi][ni][2]); h4.w = f2u(acc[mi][ni][3]);
                *(ushort4*)&((u16*)Cp)[(size_t)col*ldc + row0] = h4;
            }
        }
        return;
    }

    #pragma unroll
    for (int mi = 0; mi < 4; ++mi){
        #pragma unroll
        for (int reg = 0; reg < 4; ++reg){
            int row = m0 + wr + mi*16 + quad*4 + reg;
            #pragma unroll
            for (int ni = 0; ni < 4; ++ni){
                int col = n0 + wc + ni*16 + n16;
                float v = acc[mi][ni][reg];
                if (bias) v += bias[col];
                if (flags & GF_GELU)  v = 0.5f*v*(1.f + erff(v*0.70710678118f));
                if (flags & GF_GLU)   v = u2f(glu[(size_t)row*512 + col]) / (1.f + __expf(-v));
                if (flags & GF_RSCOL) v *= rs[(size_t)row*4 + (col >> 10)];
                size_t ci = (size_t)row*ldc + col;
                if (flags & GF_ACCUM)       ((float*)Cp)[ci] += v;
                else if (flags & GF_F32OUT) ((float*)Cp)[ci]  = v;
                else                        ((u16*)Cp)[ci]    = f2u(v);
            }
        }
    }
}

// ------------------------------------------------------------------
// MFMA flash attention, causal, dh=64, 8 heads. 128-row Q-tile per block,
// wave w owns 2 bands of 16 rows. Q frags in registers; K/V^T/P in
// XOR-swizzled LDS (mgemm layout). V is pre-transposed globally (VT[512,8192]).
__global__ __launch_bounds__(256) void flash_kernel(
    const u16* __restrict__ QK,   // [8192,1024]: cols 0..511 Q, 512..1023 K
    const u16* __restrict__ VT,   // [512,8192]
    u16* __restrict__ O)          // [8192,512]
{
    int bid = blockIdx.x;
    int qt = 15 - (bid & 15);          // heavy tiles first
    int h = (bid >> 4) & 7, b = bid >> 7;
    __shared__ u16 Ks[64*64];
    __shared__ u16 Vt[64*64];
    __shared__ u16 Ps[4][32*64];
    int tid = threadIdx.x;
    int wave = tid >> 6, lane = tid & 63;
    int n16 = lane & 15, quad = lane >> 4;
    size_t btok = (size_t)b*2048;
    size_t tok0 = btok + qt*128;
    int rowbase[2];
    rowbase[0] = qt*128 + wave*32;
    rowbase[1] = rowbase[0] + 16;

    short8 aq[2][2];
    #pragma unroll
    for (int mi = 0; mi < 2; ++mi)
        #pragma unroll
        for (int ks = 0; ks < 2; ++ks)
            aq[mi][ks] = *(const short8*)&QK[(tok0 + wave*32 + mi*16 + n16)*1024
                                            + h*64 + ks*32 + quad*8];

    float m_st[2][4], l_st[2][4];
    #pragma unroll
    for (int mi = 0; mi < 2; ++mi)
        #pragma unroll
        for (int r = 0; r < 4; ++r){ m_st[mi][r] = -3.0e38f; l_st[mi][r] = 0.f; }
    f32x4 ov[2][4] = {};

    int nkt = 2*qt + 2;
    for (int kt = 0; kt < nkt; ++kt){
        __syncthreads();
        {   // stage K and V^T tiles (swizzled groups of 8 u16)
            int r = tid >> 2;
            int g0 = (tid & 3) * 2;
            const uint4* kp = (const uint4*)&QK[(btok + kt*64 + r)*1024 + 512 + h*64 + g0*8];
            uint4 ka = kp[0], kb = kp[1];
            *(uint4*)&Ks[r*64 + ((g0  ) ^ (r&7))*8] = ka;
            *(uint4*)&Ks[r*64 + ((g0+1) ^ (r&7))*8] = kb;
            const uint4* vp = (const uint4*)&VT[(size_t)(h*64 + r)*8192 + btok + kt*64 + g0*8];
            uint4 va = vp[0], vb = vp[1];
            *(uint4*)&Vt[r*64 + ((g0  ) ^ (r&7))*8] = va;
            *(uint4*)&Vt[r*64 + ((g0+1) ^ (r&7))*8] = vb;
        }
        __syncthreads();

        #pragma unroll
        for (int mi = 0; mi < 2; ++mi){
            if (kt*64 > rowbase[mi] + 15) continue;    // fully-masked band
            f32x4 s[4];
            #pragma unroll
            for (int ct = 0; ct < 4; ++ct){
                f32x4 a = {};
                #pragma unroll
                for (int ks = 0; ks < 2; ++ks){
                    short8 bk = *(const short8*)&Ks[(ct*16+n16)*64 + (((ks*4+quad) ^ (n16&7))*8)];
                    a = mfma16(aq[mi][ks], bk, a);
                }
                s[ct] = a * 0.125f;                    // 1/sqrt(64)
            }
            if (kt*64 + 63 > rowbase[mi]){             // diagonal tile: causal mask
                #pragma unroll
                for (int ct = 0; ct < 4; ++ct){
                    int col = kt*64 + ct*16 + n16;
                    #pragma unroll
                    for (int r = 0; r < 4; ++r)
                        if (col > rowbase[mi] + quad*4 + r) s[ct][r] = -3.0e38f;
                }
            }
            #pragma unroll
            for (int r = 0; r < 4; ++r){
                float mx = fmaxf(fmaxf(s[0][r], s[1][r]), fmaxf(s[2][r], s[3][r]));
                #pragma unroll
                for (int off = 1; off < 16; off <<= 1) mx = fmaxf(mx, __shfl_xor(mx, off));
                float mn = fmaxf(m_st[mi][r], mx);
                float al = __expf(m_st[mi][r] - mn);
                m_st[mi][r] = mn;
                float sum = 0.f;
                #pragma unroll
                for (int ct = 0; ct < 4; ++ct){
                    float p = __expf(s[ct][r] - mn);
                    s[ct][r] = p; sum += p;
                }
                #pragma unroll
                for (int off = 1; off < 16; off <<= 1) sum += __shfl_xor(sum, off);
                l_st[mi][r] = l_st[mi][r]*al + sum;
                #pragma unroll
                for (int dt = 0; dt < 4; ++dt) ov[mi][dt][r] *= al;
            }
            // P band -> per-wave swizzled LDS
            #pragma unroll
            for (int ct = 0; ct < 4; ++ct){
                int gg = ct*2 + (n16 >> 3);
                #pragma unroll
                for (int r = 0; r < 4; ++r){
                    int row = mi*16 + quad*4 + r;
                    Ps[wave][row*64 + ((gg ^ (row&7))*8) + (n16 & 7)] = f2u(s[ct][r]);
                }
            }
        }
        // O += P V  (per-wave; same-wave LDS write->read, DS ops in order)
        #pragma unroll
        for (int mi = 0; mi < 2; ++mi){
            if (kt*64 > rowbase[mi] + 15) continue;
            short8 ap[2];
            #pragma unroll
            for (int ks = 0; ks < 2; ++ks){
                int row = mi*16 + n16;
                ap[ks] = *(const short8*)&Ps[wave][row*64 + (((ks*4+quad) ^ (n16&7))*8)];
            }
            #pragma unroll
            for (int dt = 0; dt < 4; ++dt)
                #pragma unroll
                for (int ks = 0; ks < 2; ++ks){
                    short8 bv = *(const short8*)&Vt[(dt*16+n16)*64 + (((ks*4+quad) ^ (n16&7))*8)];
                    ov[mi][dt] = mfma16(ap[ks], bv, ov[mi][dt]);
                }
        }
    }
    #pragma unroll
    for (int mi = 0; mi < 2; ++mi)
        #pragma unroll
        for (int r = 0; r < 4; ++r){
            float inv = 1.f / l_st[mi][r];
            size_t row = tok0 + wave*32 + mi*16 + quad*4 + r;
            #pragma unroll
            for (int dt = 0; dt < 4; ++dt)
                O[row*512 + h*64 + dt*16 + n16] = f2u(ov[mi][dt][r] * inv);
        }
}

// ------------------------------------------------------------------
// x1h = bf16( rmsnorm(x + y_bf16) * scale )
__global__ __launch_bounds__(256) void rmsnorm_kernel(
    const float* __restrict__ x, const u16* __restrict__ y,
    const float* __restrict__ scale, u16* __restrict__ out)
{
    int tok = blockIdx.x, tid = threadIdx.x;
    size_t base = (size_t)tok * 512;
    float v0 = x[base+tid]     + u2f(y[base+tid]);
    float v1 = x[base+tid+256] + u2f(y[base+tid+256]);
    float ss = v0*v0 + v1*v1;
    for (int off = 32; off; off >>= 1) ss += __shfl_down(ss, off);
    __shared__ float ws[4];
    if ((tid & 63) == 0) ws[tid >> 6] = ss;
    __syncthreads();
    float rstd = rsqrtf((ws[0]+ws[1]+ws[2]+ws[3])*(1.f/512.f) + 1e-6f);
    out[base+tid]     = f2u(scale[tid]     * v0 * rstd);
    out[base+tid+256] = f2u(scale[tid+256] * v1 * rstd);
}

// out_fp32 = rmsnorm(x1h + moe + ROUT@b2) * scale
__global__ __launch_bounds__(256) void final_kernel(
    const u16* __restrict__ x1, const float* __restrict__ moe,
    const float* __restrict__ rout, const float* __restrict__ b2,
    const float* __restrict__ scale, float* __restrict__ out)
{
    int tok = blockIdx.x, tid = threadIdx.x;
    size_t base = (size_t)tok * 512;
    float r0 = rout[tok*4+0], r1 = rout[tok*4+1], r2 = rout[tok*4+2], r3 = rout[tok*4+3];
    float bb0 = r0*b2[tid]     + r1*b2[512+tid]     + r2*b2[1024+tid]     + r3*b2[1536+tid];
    float bb1 = r0*b2[tid+256] + r1*b2[768+tid]     + r2*b2[1280+tid]     + r3*b2[1792+tid];
    float v0 = u2f(x1[base+tid])     + moe[base+tid]     + bb0;
    float v1 = u2f(x1[base+tid+256]) + moe[base+tid+256] + bb1;
    float ss = v0*v0 + v1*v1;
    for (int off = 32; off; off >>= 1) ss += __shfl_down(ss, off);
    __shared__ float ws[4];
    if ((tid & 63) == 0) ws[tid >> 6] = ss;
    __syncthreads();
    float rstd = rsqrtf((ws[0]+ws[1]+ws[2]+ws[3])*(1.f/512.f) + 1e-6f);
    out[base+tid]     = scale[tid]     * v0 * rstd;
    out[base+tid+256] = scale[tid+256] * v1 * rstd;
}

// router: softmax(x1h @ wr + br), one wave per token
__global__ __launch_bounds__(256) void router_kernel(
    const u16* __restrict__ x1, const float* __restrict__ wr,
    const float* __restrict__ br, float* __restrict__ rout)
{
    int wid = threadIdx.x >> 6, lane = threadIdx.x & 63;
    int tok = blockIdx.x*4 + wid;
    const u16* xp = x1 + (size_t)tok*512;
    float p0=0.f, p1=0.f, p2=0.f, p3=0.f;
    for (int d = lane; d < 512; d += 64){
        float xv = u2f(xp[d]);
        p0 += xv*wr[d*4+0]; p1 += xv*wr[d*4+1];
        p2 += xv*wr[d*4+2]; p3 += xv*wr[d*4+3];
    }
    for (int off = 32; off; off >>= 1){
        p0 += __shfl_down(p0,off); p1 += __shfl_down(p1,off);
        p2 += __shfl_down(p2,off); p3 += __shfl_down(p3,off);
    }
    if (lane == 0){
        p0 += br[0]; p1 += br[1]; p2 += br[2]; p3 += br[3];
        float mx = fmaxf(fmaxf(p0,p1), fmaxf(p2,p3));
        float e0=__expf(p0-mx), e1=__expf(p1-mx), e2=__expf(p2-mx), e3=__expf(p3-mx);
        float inv = 1.f/(e0+e1+e2+e3);
        rout[tok*4+0]=e0*inv; rout[tok*4+1]=e1*inv;
        rout[tok*4+2]=e2*inv; rout[tok*4+3]=e3*inv;
    }
}

// ------------------------------------------------------------------
extern "C" void kernel_launch(void* const* d_in, const int* in_sizes, int n_in,
                              void* d_out, int out_size, void* d_ws, size_t ws_size,
                              hipStream_t stream)
{
    const float* x    = (const float*)d_in[0];
    const float* mp_w = (const float*)d_in[3];
    const float* mp_b = (const float*)d_in[4];
    const float* fu_w = (const float*)d_in[5];
    const float* fu_b = (const float*)d_in[6];
    const float* wc   = (const float*)d_in[7];
    const float* wk   = (const float*)d_in[8];
    const float* wv   = (const float*)d_in[9];
    const float* wq   = (const float*)d_in[10];
    const float* wo   = (const float*)d_in[11];
    const float* s1   = (const float*)d_in[12];
    const float* s2   = (const float*)d_in[13];
    const float* wr   = (const float*)d_in[14];
    const float* br   = (const float*)d_in[15];
    const float* wg   = (const float*)d_in[16];
    const float* bg   = (const float*)d_in[17];
    const float* w1   = (const float*)d_in[18];
    const float* b1   = (const float*)d_in[19];
    const float* w2   = (const float*)d_in[20];
    const float* b2   = (const float*)d_in[21];

    char* wsb = (char*)d_ws;
    const size_t MB = 1024*1024;
    // persistent weights/state (13 MB)
    u16*   wqkT   = (u16*)(wsb + 0);                 // [1024,512]: wqT rows 0..511, WckT rows 512..1023
    u16*   wcvT   = (u16*)(wsb + 1*MB);              // [512,512]
    u16*   woT    = (u16*)(wsb + (3*MB)/2);          // [512,512]
    u16*   wgT    = (u16*)(wsb + 2*MB);              // [512,512]
    u16*   WfuT2  = (u16*)(wsb + (5*MB)/2);          // [512,1024] fused fusion weight
    u16*   fuBT   = (u16*)(wsb + (7*MB)/2);          // [512,512]
    u16*   mp_wB  = (u16*)(wsb + 4*MB);              // [512,512] row-major
    u16*   w1T    = (u16*)(wsb + (9*MB)/2);          // [4096,512]
    u16*   w2Ts   = (u16*)(wsb + (17*MB)/2);         // [512,4096]
    float* fubias = (float*)(wsb + (25*MB)/2);       // 512
    float* ROUT   = (float*)(wsb + (25*MB)/2 + 4096);// 8192x4
    // big rotating buffers (high-water 77 MB)
    u16*   XFcat = (u16*)(wsb + 13*MB);              // [8192,1024] -> dead after XFU
    float* MOE   = (float*)(wsb + 13*MB);            // [8192,512] fp32 (w2 phase)
    u16*   S3    = (u16*)(wsb + 13*MB);              // [8192,512] (wo out; dead after rmsnorm)
    u16*   XFU   = (u16*)(wsb + 29*MB);              // [8192,512] -> XG reuses
    u16*   XG    = (u16*)(wsb + 29*MB);
    u16*   QKb   = (u16*)(wsb + 37*MB);              // [8192,1024]
    u16*   Hb    = (u16*)(wsb + 37*MB);              // [8192,2048] (w1/w2 phase, 32MB)
    u16*   VbT   = (u16*)(wsb + 53*MB);              // [512,8192]
    u16*   ATT   = (u16*)(wsb + 61*MB);              // [8192,512]
    u16*   x1h   = (u16*)(wsb + 69*MB);              // [8192,512]

    auto mg = [&](const u16* A, int lda, const u16* Bt, int ldb, const float* bias,
                  const float* rs, const u16* glu, void* C, int ldc,
                  int M, int N, int K, int flags){
        dim3 g(N/128, M/128);
        mgemm_kernel<<<g, 256, 0, stream>>>(A, lda, Bt, ldb, bias, rs, glu, C, ldc, K, flags);
    };

    // ---- prepass (re-run every call: ws is re-poisoned by harness)
    TJobs JJ; JJ.n = 11;
    auto setj = [&](int i, const float* src, u16* dst, int K, int N, int ldout, int coloff){
        JJ.j[i] = TJob{src, dst, K, N, ldout, coloff, (K/32)*(N/32)};
    };
    setj(0, wq,            wqkT,  512,  512,  512, 0);
    setj(1, wo,            woT,   512,  512,  512, 0);
    setj(2, wg,            wgT,   512,  512,  512, 0);
    setj(3, fu_w,          WfuT2, 512,  512, 1024, 0);          // fuA^T -> cols 0..511
    setj(4, fu_w + 512*512,fuBT,  512,  512,  512, 0);          // fuB^T
    int nt = 5*256;
    for (int e = 0; e < 4; ++e){
        setj(5+e, w1 + (size_t)e*512*1024, w1T + (size_t)e*1024*512, 512, 1024, 512, 0);
        nt += 512;
    }
    // w2: pack jobs 9,10 per-pair? need 4 jobs but struct holds 12 — use indices 9..12? n=11 max 12
    // jobs 9..12 would exceed; fold w2 into remaining slots:
    JJ.n = 12;
    setj(9,  w2,                      w2Ts, 1024, 512, 4096, 0);
    setj(10, w2 + (size_t)1*1024*512, w2Ts, 1024, 512, 4096, 1024);
    setj(11, w2 + (size_t)2*1024*512, w2Ts, 1024, 512, 4096, 2048);
    nt += 3*512;
    // 4th w2 expert via second tiny dispatch below
    tconv_all_kernel<<<nt, 256, 0, stream>>>(JJ);
    TJobs J2; J2.n = 1;
    J2.j[0] = TJob{w2 + (size_t)3*1024*512, w2Ts, 1024, 512, 4096, 3072, 512};
    tconv_all_kernel<<<512, 256, 0, stream>>>(J2);
    convert_kernel<<<512*512/256, 256, 0, stream>>>(mp_w, mp_wB);
    sgemm_kernel<<<dim3(8,8), 256, 0, stream>>>(wc, wk, wqkT + 512*512, 512, 32); // WckT rows 512..
    sgemm_kernel<<<dim3(8,8), 256, 0, stream>>>(wc, wv, wcvT, 512, 32);           // WcvT
    biasfold_kernel<<<512, 256, 0, stream>>>(fu_b, mp_b, fu_w, fubias);
    // F1^T = (mp_w@fuB)^T into WfuT2 cols 512..1023
    mg(fuBT, 512, mp_wB, 512, 0, 0, 0, WfuT2 + 512, 1024, 512, 512, 512, 0);

    // ---- main pipeline
    gatepool_kernel<<<(TOK/16)*512/256, 256, 0, stream>>>(x, XFcat);
    mg(XFcat, 1024, WfuT2, 1024, fubias, 0, 0, XFU, 512, TOK, 512, 1024, 0);   // xfu
    mg(XFU, 512, wqkT, 512, 0, 0, 0, QKb, 1024, TOK, 1024, 512, 0);            // [Q|K]
    mg(XFU, 512, wcvT, 512, 0, 0, 0, VbT, 8192, TOK, 512, 512, GF_TRANS);      // V^T
    flash_kernel<<<512, 256, 0, stream>>>(QKb, VbT, ATT);
    mg(ATT, 512, woT, 512, 0, 0, 0, S3, 512, TOK, 512, 512, 0);                // attn@wo
    rmsnorm_kernel<<<TOK, 256, 0, stream>>>(x, S3, s1, x1h);                   // x1
    router_kernel<<<TOK/4, 256, 0, stream>>>(x1h, wr, br, ROUT);
    mg(x1h, 512, wgT, 512, bg, 0, x1h, XG, 512, TOK, 512, 512, GF_GLU);        // xg
    for (int p = 0; p < 2; ++p){
        mg(XG, 512, w1T + (size_t)p*2048*512, 512, b1 + p*2048, ROUT + p*2, 0,
           Hb, 2048, TOK, 2048, 512, GF_GELU | GF_RSCOL);                      // H (router-scaled)
        mg(Hb, 2048, w2Ts + p*2048, 4096, 0, 0, 0,
           MOE, 512, TOK, 512, 2048, p ? GF_ACCUM : GF_F32OUT);                // MOE
    }
    final_kernel<<<TOK, 256, 0, stream>>>(x1h, MOE, ROUT, b2, s2, (float*)d_out);
}

// Round 5
// 631.274 us; speedup vs baseline: 4.7622x; 1.1040x over previous
//
#include <hip/hip_runtime.h>
#include <math.h>

#define B_   4
#define T_   2048
#define D_   512
#define TOK  (B_*T_)      // 8192 tokens
#define TL_  2045         // N_BLOCKS*(T//N_BLOCKS) = 5*409
#define GATE 0.2f         // softmax(...).mean(-1) over same axis == 1/5

typedef unsigned short u16;
typedef __attribute__((ext_vector_type(8))) short short8;   // 8 bf16 = 4 VGPRs
typedef __attribute__((ext_vector_type(4))) float f32x4;

static __device__ __forceinline__ u16 f2u(float f){      // fp32 -> bf16 (RNE)
    union { float f; unsigned u; } a; a.f = f;
    unsigned r = a.u + 0x7fffu + ((a.u >> 16) & 1u);
    return (u16)(r >> 16);
}
static __device__ __forceinline__ float u2f(u16 u){
    union { unsigned u; float f; } a; a.u = ((unsigned)u) << 16;
    return a.f;
}
static __device__ __forceinline__ f32x4 mfma16(short8 a, short8 b, f32x4 c){
    return __builtin_amdgcn_mfma_f32_16x16x32_bf16(a, b, c, 0, 0, 0);
}
static __device__ __forceinline__ void glds16(const u16* g, u16* l){
    __builtin_amdgcn_global_load_lds((const __attribute__((address_space(1))) void*)g,
                                     (__attribute__((address_space(3))) void*)l, 16, 0, 0);
}

// ------------------------------------------------------------------
// gate + pool fused: XFcat[:,0:512]=bf16(0.2*x masked), XFcat[:,512:]=bf16(pool)
__global__ __launch_bounds__(256) void gatepool_kernel(
    const float* __restrict__ x, u16* __restrict__ xfcat)
{
    int idx = blockIdx.x*256 + threadIdx.x;
    int d = idx & 511, g = idx >> 9;
    int b = g >> 7, t0 = (g & 127) << 4;
    const float* xp = x + ((size_t)b*2048)*512 + d;
    float v[30];
    #pragma unroll
    for (int j = 0; j < 30; ++j){
        int u = t0 - 7 + j;
        v[j] = (u >= 0 && u < TL_) ? xp[(size_t)u*512] : 0.f;
    }
    float p[31]; p[0] = 0.f;
    #pragma unroll
    for (int j = 0; j < 30; ++j) p[j+1] = p[j] + v[j];
    u16* xc = xfcat + ((size_t)(b*2048 + t0))*1024 + d;
    #pragma unroll
    for (int i = 0; i < 16; ++i){
        int t = t0 + i;
        float sum = p[i+15] - p[i];                 // u in [t-7, t+7]
        int lo = t-7; if (lo < 0) lo = 0;
        int hi = t+7; if (hi > 2047) hi = 2047;
        xc[(size_t)i*1024]       = f2u((t < TL_) ? GATE*v[i+7] : 0.f);
        xc[(size_t)i*1024 + 512] = f2u(GATE * sum / (float)(hi - lo + 1));
    }
}

// ------------------------------------------------------------------
// batched transpose+convert: src fp32 [K,N] -> dst[n*ldout+coloff+k] = bf16(scale*src)
struct TJob { const float* src; u16* dst; int K, N, ldout, coloff, tiles; float scale; };
struct TJobs { TJob j[12]; int n; };

__global__ __launch_bounds__(256) void tconv_all_kernel(TJobs JJ){
    __shared__ float t[32][33];
    int idx = blockIdx.x;
    int jb = 0;
    while (jb < JJ.n - 1 && idx >= JJ.j[jb].tiles){ idx -= JJ.j[jb].tiles; ++jb; }
    TJob J = JJ.j[jb];
    int tX = J.N >> 5;
    int k0 = (idx / tX) * 32, n0 = (idx % tX) * 32;
    int tx = threadIdx.x & 31, ty = threadIdx.x >> 5;
    #pragma unroll
    for (int i = 0; i < 32; i += 8)
        t[ty+i][tx] = J.src[(size_t)(k0+ty+i)*J.N + n0+tx];
    __syncthreads();
    #pragma unroll
    for (int i = 0; i < 32; i += 8)
        J.dst[(size_t)(n0+ty+i)*J.ldout + J.coloff + k0+tx] = f2u(J.scale * t[tx][ty+i]);
}

// fp32 -> bf16 plain convert
__global__ void convert_kernel(const float* __restrict__ in, u16* __restrict__ out){
    int idx = blockIdx.x*256 + threadIdx.x;
    out[idx] = f2u(in[idx]);
}

// fubias[n] = fu_b[n] + sum_d mp_b[d] * fu_w[512+d][n]
__global__ __launch_bounds__(256) void biasfold_kernel(
    const float* __restrict__ fu_b, const float* __restrict__ mp_b,
    const float* __restrict__ fu_w, float* __restrict__ out)
{
    int n = blockIdx.x, tid = threadIdx.x;
    float s = mp_b[tid]*fu_w[(size_t)(512+tid)*512 + n]
            + mp_b[tid+256]*fu_w[(size_t)(768+tid)*512 + n];
    for (int off = 32; off; off >>= 1) s += __shfl_down(s, off);
    __shared__ float ws[4];
    if ((tid & 63) == 0) ws[tid >> 6] = s;
    __syncthreads();
    if (tid == 0) out[n] = fu_b[n] + ws[0]+ws[1]+ws[2]+ws[3];
}

// small fp32 GEMM writing bf16 TRANSPOSED: dstT[n*ldT + m] = (A@B)[m][n]
__global__ __launch_bounds__(256) void sgemm_kernel(const float* __restrict__ A,
    const float* __restrict__ B, u16* __restrict__ dstT, int ldT, int K){
    __shared__ float As[16][65];
    __shared__ float Bs[16][65];
    int tid = threadIdx.x;
    int tx = tid & 15, ty = tid >> 4;
    int m0 = blockIdx.y*64, n0 = blockIdx.x*64;
    int arow = tid >> 2, akq = (tid & 3) * 4;
    int bk = tid >> 4, bn = (tid & 15) * 4;
    float acc[4][4] = {};
    for (int k0 = 0; k0 < K; k0 += 16){
        const float* Ap = A + (size_t)(m0+arow)*K + k0 + akq;
        As[akq+0][arow]=Ap[0]; As[akq+1][arow]=Ap[1];
        As[akq+2][arow]=Ap[2]; As[akq+3][arow]=Ap[3];
        const float* Bp = B + (size_t)(k0+bk)*512 + n0 + bn;
        Bs[bk][bn+0]=Bp[0]; Bs[bk][bn+1]=Bp[1];
        Bs[bk][bn+2]=Bp[2]; Bs[bk][bn+3]=Bp[3];
        __syncthreads();
        #pragma unroll
        for (int kk = 0; kk < 16; ++kk){
            float av[4], bv[4];
            #pragma unroll
            for (int i=0;i<4;++i) av[i]=As[kk][ty*4+i];
            #pragma unroll
            for (int j=0;j<4;++j) bv[j]=Bs[kk][tx*4+j];
            #pragma unroll
            for (int i=0;i<4;++i)
                #pragma unroll
                for (int j=0;j<4;++j) acc[i][j] += av[i]*bv[j];
        }
        __syncthreads();
    }
    #pragma unroll
    for (int i=0;i<4;++i)
        #pragma unroll
        for (int j=0;j<4;++j)
            dstT[(size_t)(n0+tx*4+j)*ldT + m0+ty*4+i] = f2u(acc[i][j]);
}

// ------------------------------------------------------------------
// bf16 MFMA GEMM: C[M,N] = op(A[M,K] @ Bt[N,K]^T + bias), MTx128 tile, BK=64.
// MT=128: 4 waves each 64x64 (1 block/CU class). MT=64: each wave 32x64,
// grid doubles -> 2+ blocks/CU for inter-block latency hiding.
#define GF_GELU   1
#define GF_ACCUM  2
#define GF_RSCOL  4
#define GF_GLU    8
#define GF_F32OUT 16
#define GF_TRANS  32

template<int MT>
__global__ __launch_bounds__(256) void mgemm_kernel(
    const u16* __restrict__ A, int lda, const u16* __restrict__ Bt, int ldb,
    const float* __restrict__ bias, const float* __restrict__ rs,
    const u16* __restrict__ glu, void* __restrict__ Cp, int ldc,
    int K, int flags)
{
    constexpr int MI = MT/32;            // m-tiles per wave (16 rows each)
    __shared__ u16 As[MT*64];
    __shared__ u16 Bs[128*64];
    int tid = threadIdx.x;
    int wave = tid >> 6, lane = tid & 63;
    int n16 = lane & 15, quad = lane >> 4;
    int m0 = blockIdx.y * MT, n0 = blockIdx.x * 128;
    int wr = (wave >> 1) * (MT/2), wc = (wave & 1) * 64;

    f32x4 acc[MI][4] = {};

    for (int k0 = 0; k0 < K; k0 += 64){
        #pragma unroll
        for (int i = 0; i < MT/32; ++i){
            int s = i*256 + tid;
            int row = s >> 3, g = (s & 7) ^ (row & 7);
            glds16(A + (size_t)(m0+row)*lda + k0 + g*8, As + (size_t)s*8);
        }
        #pragma unroll
        for (int i = 0; i < 4; ++i){
            int s = i*256 + tid;
            int row = s >> 3, g = (s & 7) ^ (row & 7);
            glds16(Bt + (size_t)(n0+row)*ldb + k0 + g*8, Bs + (size_t)s*8);
        }
        __syncthreads();
        #pragma unroll
        for (int ks = 0; ks < 2; ++ks){
            short8 af[MI], bf[4];
            #pragma unroll
            for (int mi = 0; mi < MI; ++mi){
                int row = wr + mi*16 + n16;
                int g = (ks*4 + quad) ^ (row & 7);
                af[mi] = *(const short8*)&As[row*64 + g*8];
            }
            #pragma unroll
            for (int ni = 0; ni < 4; ++ni){
                int row = wc + ni*16 + n16;
                int g = (ks*4 + quad) ^ (row & 7);
                bf[ni] = *(const short8*)&Bs[row*64 + g*8];
            }
            #pragma unroll
            for (int mi = 0; mi < MI; ++mi)
                #pragma unroll
                for (int ni = 0; ni < 4; ++ni)
                    acc[mi][ni] = mfma16(af[mi], bf[ni], acc[mi][ni]);
        }
        __syncthreads();
    }

    if (flags & GF_TRANS){
        // C^T store (for V^T): Cp[col*ldc + row0..row0+3]
        #pragma unroll
        for (int mi = 0; mi < MI; ++mi){
            int row0 = m0 + wr + mi*16 + quad*4;
            #pragma unroll
            for (int ni = 0; ni < 4; ++ni){
                int col = n0 + wc + ni*16 + n16;
                ushort4 h4;
                h4.x = f2u(acc[mi][ni][0]); h4.y = f2u(acc[mi][ni][1]);
                h4.z = f2u(acc[mi][ni][2]); h4.w = f2u(acc[mi][ni][3]);
                *(ushort4*)&((u16*)Cp)[(size_t)col*ldc + row0] = h4;
            }
        }
        return;
    }

    #pragma unroll
    for (int mi = 0; mi < MI; ++mi){
        #pragma unroll
        for (int reg = 0; reg < 4; ++reg){
            int row = m0 + wr + mi*16 + quad*4 + reg;
            #pragma unroll
            for (int ni = 0; ni < 4; ++ni){
                int col = n0 + wc + ni*16 + n16;
                float v = acc[mi][ni][reg];
                if (bias) v += bias[col];
                if (flags & GF_GELU)  v = 0.5f*v*(1.f + erff(v*0.70710678118f));
                if (flags & GF_GLU)   v = u2f(glu[(size_t)row*512 + col]) / (1.f + __expf(-v));
                if (flags & GF_RSCOL) v *= rs[(size_t)row*4 + (col >> 10)];
                size_t ci = (size_t)row*ldc + col;
                if (flags & GF_ACCUM)       ((float*)Cp)[ci] += v;
                else if (flags & GF_F32OUT) ((float*)Cp)[ci]  = v;
                else                        ((u16*)Cp)[ci]    = f2u(v);
            }
        }
    }
}

// ------------------------------------------------------------------
// MFMA flash attention, causal, dh=64, 8 heads. 128-row Q-tile per block,
// wave w owns 2 bands of 16 rows. Q (pre-scaled by 1/8 via wq) in registers;
// K/V^T/P in XOR-swizzled LDS. Globally heavy-first block order.
__global__ __launch_bounds__(256) void flash_kernel(
    const u16* __restrict__ QK,   // [8192,1024]: cols 0..511 Q, 512..1023 K
    const u16* __restrict__ VT,   // [512,8192]
    u16* __restrict__ O)          // [8192,512]
{
    int bid = blockIdx.x;
    int qt = 15 - (bid >> 5);          // global heavy-first
    int bh = bid & 31;
    int h = bh & 7, b = bh >> 3;
    __shared__ u16 Ks[64*64];
    __shared__ u16 Vt[64*64];
    __shared__ u16 Ps[4][32*64];
    int tid = threadIdx.x;
    int wave = tid >> 6, lane = tid & 63;
    int n16 = lane & 15, quad = lane >> 4;
    size_t btok = (size_t)b*2048;
    size_t tok0 = btok + qt*128;
    int rowbase[2];
    rowbase[0] = qt*128 + wave*32;
    rowbase[1] = rowbase[0] + 16;

    short8 aq[2][2];
    #pragma unroll
    for (int mi = 0; mi < 2; ++mi)
        #pragma unroll
        for (int ks = 0; ks < 2; ++ks)
            aq[mi][ks] = *(const short8*)&QK[(tok0 + wave*32 + mi*16 + n16)*1024
                                            + h*64 + ks*32 + quad*8];

    float m_st[2][4], l_st[2][4];
    #pragma unroll
    for (int mi = 0; mi < 2; ++mi)
        #pragma unroll
        for (int r = 0; r < 4; ++r){ m_st[mi][r] = -3.0e38f; l_st[mi][r] = 0.f; }
    f32x4 ov[2][4] = {};

    int nkt = 2*qt + 2;
    for (int kt = 0; kt < nkt; ++kt){
        __syncthreads();
        {   // stage K and V^T tiles (swizzled groups of 8 u16)
            int r = tid >> 2;
            int g0 = (tid & 3) * 2;
            const uint4* kp = (const uint4*)&QK[(btok + kt*64 + r)*1024 + 512 + h*64 + g0*8];
            uint4 ka = kp[0], kb = kp[1];
            *(uint4*)&Ks[r*64 + ((g0  ) ^ (r&7))*8] = ka;
            *(uint4*)&Ks[r*64 + ((g0+1) ^ (r&7))*8] = kb;
            const uint4* vp = (const uint4*)&VT[(size_t)(h*64 + r)*8192 + btok + kt*64 + g0*8];
            uint4 va = vp[0], vb = vp[1];
            *(uint4*)&Vt[r*64 + ((g0  ) ^ (r&7))*8] = va;
            *(uint4*)&Vt[r*64 + ((g0+1) ^ (r&7))*8] = vb;
        }
        __syncthreads();

        #pragma unroll
        for (int mi = 0; mi < 2; ++mi){
            if (kt*64 > rowbase[mi] + 15) continue;    // fully-masked band
            f32x4 s[4];
            #pragma unroll
            for (int ct = 0; ct < 4; ++ct){
                f32x4 a = {};
                #pragma unroll
                for (int ks = 0; ks < 2; ++ks){
                    short8 bk = *(const short8*)&Ks[(ct*16+n16)*64 + (((ks*4+quad) ^ (n16&7))*8)];
                    a = mfma16(aq[mi][ks], bk, a);
                }
                s[ct] = a;                             // scale folded into wq
            }
            if (kt*64 + 63 > rowbase[mi]){             // diagonal tile: causal mask
                #pragma unroll
                for (int ct = 0; ct < 4; ++ct){
                    int col = kt*64 + ct*16 + n16;
                    #pragma unroll
                    for (int r = 0; r < 4; ++r)
                        if (col > rowbase[mi] + quad*4 + r) s[ct][r] = -3.0e38f;
                }
            }
            #pragma unroll
            for (int r = 0; r < 4; ++r){
                float mx = fmaxf(fmaxf(s[0][r], s[1][r]), fmaxf(s[2][r], s[3][r]));
                #pragma unroll
                for (int off = 1; off < 16; off <<= 1) mx = fmaxf(mx, __shfl_xor(mx, off));
                float mn = fmaxf(m_st[mi][r], mx);
                float al = __expf(m_st[mi][r] - mn);
                m_st[mi][r] = mn;
                float sum = 0.f;
                #pragma unroll
                for (int ct = 0; ct < 4; ++ct){
                    float p = __expf(s[ct][r] - mn);
                    s[ct][r] = p; sum += p;
                }
                #pragma unroll
                for (int off = 1; off < 16; off <<= 1) sum += __shfl_xor(sum, off);
                l_st[mi][r] = l_st[mi][r]*al + sum;
                #pragma unroll
                for (int dt = 0; dt < 4; ++dt) ov[mi][dt][r] *= al;
            }
            // P band -> per-wave swizzled LDS
            #pragma unroll
            for (int ct = 0; ct < 4; ++ct){
                int gg = ct*2 + (n16 >> 3);
                #pragma unroll
                for (int r = 0; r < 4; ++r){
                    int row = mi*16 + quad*4 + r;
                    Ps[wave][row*64 + ((gg ^ (row&7))*8) + (n16 & 7)] = f2u(s[ct][r]);
                }
            }
        }
        // O += P V  (per-wave; same-wave LDS write->read ordering)
        #pragma unroll
        for (int mi = 0; mi < 2; ++mi){
            if (kt*64 > rowbase[mi] + 15) continue;
            short8 ap[2];
            #pragma unroll
            for (int ks = 0; ks < 2; ++ks){
                int row = mi*16 + n16;
                ap[ks] = *(const short8*)&Ps[wave][row*64 + (((ks*4+quad) ^ (n16&7))*8)];
            }
            #pragma unroll
            for (int dt = 0; dt < 4; ++dt)
                #pragma unroll
                for (int ks = 0; ks < 2; ++ks){
                    short8 bv = *(const short8*)&Vt[(dt*16+n16)*64 + (((ks*4+quad) ^ (n16&7))*8)];
                    ov[mi][dt] = mfma16(ap[ks], bv, ov[mi][dt]);
                }
        }
    }
    #pragma unroll
    for (int mi = 0; mi < 2; ++mi)
        #pragma unroll
        for (int r = 0; r < 4; ++r){
            float inv = 1.f / l_st[mi][r];
            size_t row = tok0 + wave*32 + mi*16 + quad*4 + r;
            #pragma unroll
            for (int dt = 0; dt < 4; ++dt)
                O[row*512 + h*64 + dt*16 + n16] = f2u(ov[mi][dt][r] * inv);
        }
}

// ------------------------------------------------------------------
// x1h = bf16( rmsnorm(x + y_bf16) * scale )
__global__ __launch_bounds__(256) void rmsnorm_kernel(
    const float* __restrict__ x, const u16* __restrict__ y,
    const float* __restrict__ scale, u16* __restrict__ out)
{
    int tok = blockIdx.x, tid = threadIdx.x;
    size_t base = (size_t)tok * 512;
    float v0 = x[base+tid]     + u2f(y[base+tid]);
    float v1 = x[base+tid+256] + u2f(y[base+tid+256]);
    float ss = v0*v0 + v1*v1;
    for (int off = 32; off; off >>= 1) ss += __shfl_down(ss, off);
    __shared__ float ws[4];
    if ((tid & 63) == 0) ws[tid >> 6] = ss;
    __syncthreads();
    float rstd = rsqrtf((ws[0]+ws[1]+ws[2]+ws[3])*(1.f/512.f) + 1e-6f);
    out[base+tid]     = f2u(scale[tid]     * v0 * rstd);
    out[base+tid+256] = f2u(scale[tid+256] * v1 * rstd);
}

// out_fp32 = rmsnorm(x1h + moe + ROUT@b2) * scale
__global__ __launch_bounds__(256) void final_kernel(
    const u16* __restrict__ x1, const float* __restrict__ moe,
    const float* __restrict__ rout, const float* __restrict__ b2,
    const float* __restrict__ scale, float* __restrict__ out)
{
    int tok = blockIdx.x, tid = threadIdx.x;
    size_t base = (size_t)tok * 512;
    float r0 = rout[tok*4+0], r1 = rout[tok*4+1], r2 = rout[tok*4+2], r3 = rout[tok*4+3];
    float bb0 = r0*b2[tid]     + r1*b2[512+tid]     + r2*b2[1024+tid]     + r3*b2[1536+tid];
    float bb1 = r0*b2[tid+256] + r1*b2[768+tid]     + r2*b2[1280+tid]     + r3*b2[1792+tid];
    float v0 = u2f(x1[base+tid])     + moe[base+tid]     + bb0;
    float v1 = u2f(x1[base+tid+256]) + moe[base+tid+256] + bb1;
    float ss = v0*v0 + v1*v1;
    for (int off = 32; off; off >>= 1) ss += __shfl_down(ss, off);
    __shared__ float ws[4];
    if ((tid & 63) == 0) ws[tid >> 6] = ss;
    __syncthreads();
    float rstd = rsqrtf((ws[0]+ws[1]+ws[2]+ws[3])*(1.f/512.f) + 1e-6f);
    out[base+tid]     = scale[tid]     * v0 * rstd;
    out[base+tid+256] = scale[tid+256] * v1 * rstd;
}

// router: softmax(x1h @ wr + br), one wave per token
__global__ __launch_bounds__(256) void router_kernel(
    const u16* __restrict__ x1, const float* __restrict__ wr,
    const float* __restrict__ br, float* __restrict__ rout)
{
    int wid = threadIdx.x >> 6, lane = threadIdx.x & 63;
    int tok = blockIdx.x*4 + wid;
    const u16* xp = x1 + (size_t)tok*512;
    float p0=0.f, p1=0.f, p2=0.f, p3=0.f;
    for (int d = lane; d < 512; d += 64){
        float xv = u2f(xp[d]);
        p0 += xv*wr[d*4+0]; p1 += xv*wr[d*4+1];
        p2 += xv*wr[d*4+2]; p3 += xv*wr[d*4+3];
    }
    for (int off = 32; off; off >>= 1){
        p0 += __shfl_down(p0,off); p1 += __shfl_down(p1,off);
        p2 += __shfl_down(p2,off); p3 += __shfl_down(p3,off);
    }
    if (lane == 0){
        p0 += br[0]; p1 += br[1]; p2 += br[2]; p3 += br[3];
        float mx = fmaxf(fmaxf(p0,p1), fmaxf(p2,p3));
        float e0=__expf(p0-mx), e1=__expf(p1-mx), e2=__expf(p2-mx), e3=__expf(p3-mx);
        float inv = 1.f/(e0+e1+e2+e3);
        rout[tok*4+0]=e0*inv; rout[tok*4+1]=e1*inv;
        rout[tok*4+2]=e2*inv; rout[tok*4+3]=e3*inv;
    }
}

// ------------------------------------------------------------------
extern "C" void kernel_launch(void* const* d_in, const int* in_sizes, int n_in,
                              void* d_out, int out_size, void* d_ws, size_t ws_size,
                              hipStream_t stream)
{
    const float* x    = (const float*)d_in[0];
    const float* mp_w = (const float*)d_in[3];
    const float* mp_b = (const float*)d_in[4];
    const float* fu_w = (const float*)d_in[5];
    const float* fu_b = (const float*)d_in[6];
    const float* wc   = (const float*)d_in[7];
    const float* wk   = (const float*)d_in[8];
    const float* wv   = (const float*)d_in[9];
    const float* wq   = (const float*)d_in[10];
    const float* wo   = (const float*)d_in[11];
    const float* s1   = (const float*)d_in[12];
    const float* s2   = (const float*)d_in[13];
    const float* wr   = (const float*)d_in[14];
    const float* br   = (const float*)d_in[15];
    const float* wg   = (const float*)d_in[16];
    const float* bg   = (const float*)d_in[17];
    const float* w1   = (const float*)d_in[18];
    const float* b1   = (const float*)d_in[19];
    const float* w2   = (const float*)d_in[20];
    const float* b2   = (const float*)d_in[21];

    char* wsb = (char*)d_ws;
    const size_t MB = 1024*1024;
    // persistent weights/state (13 MB)
    u16*   wqkT   = (u16*)(wsb + 0);                 // [1024,512]: wqT(x0.125) rows 0..511, WckT rows 512..1023
    u16*   wcvT   = (u16*)(wsb + 1*MB);              // [512,512]
    u16*   woT    = (u16*)(wsb + (3*MB)/2);          // [512,512]
    u16*   wgT    = (u16*)(wsb + 2*MB);              // [512,512]
    u16*   WfuT2  = (u16*)(wsb + (5*MB)/2);          // [512,1024] fused fusion weight
    u16*   fuBT   = (u16*)(wsb + (7*MB)/2);          // [512,512]
    u16*   mp_wB  = (u16*)(wsb + 4*MB);              // [512,512] row-major
    u16*   w1T    = (u16*)(wsb + (9*MB)/2);          // [4096,512]
    u16*   w2Ts   = (u16*)(wsb + (17*MB)/2);         // [512,4096]
    float* fubias = (float*)(wsb + (25*MB)/2);       // 512
    float* ROUT   = (float*)(wsb + (25*MB)/2 + 4096);// 8192x4
    // big rotating buffers (high-water 77 MB)
    u16*   XFcat = (u16*)(wsb + 13*MB);              // [8192,1024] -> dead after XFU
    float* MOE   = (float*)(wsb + 13*MB);            // [8192,512] fp32 (w2 phase)
    u16*   S3    = (u16*)(wsb + 13*MB);              // [8192,512] (wo out; dead after rmsnorm)
    u16*   XFU   = (u16*)(wsb + 29*MB);              // [8192,512] -> XG reuses
    u16*   XG    = (u16*)(wsb + 29*MB);
    u16*   QKb   = (u16*)(wsb + 37*MB);              // [8192,1024]
    u16*   Hb    = (u16*)(wsb + 37*MB);              // [8192,2048] (w1/w2 phase, 32MB)
    u16*   VbT   = (u16*)(wsb + 53*MB);              // [512,8192]
    u16*   ATT   = (u16*)(wsb + 61*MB);              // [8192,512]
    u16*   x1h   = (u16*)(wsb + 69*MB);              // [8192,512]

    auto mg128 = [&](const u16* A, int lda, const u16* Bt, int ldb, const float* bias,
                     const float* rs, const u16* glu, void* C, int ldc,
                     int M, int N, int K, int flags){
        dim3 g(N/128, M/128);
        mgemm_kernel<128><<<g, 256, 0, stream>>>(A, lda, Bt, ldb, bias, rs, glu, C, ldc, K, flags);
    };
    auto mg64 = [&](const u16* A, int lda, const u16* Bt, int ldb, const float* bias,
                    const float* rs, const u16* glu, void* C, int ldc,
                    int M, int N, int K, int flags){
        dim3 g(N/128, M/64);
        mgemm_kernel<64><<<g, 256, 0, stream>>>(A, lda, Bt, ldb, bias, rs, glu, C, ldc, K, flags);
    };

    // ---- prepass (re-run every call: ws is re-poisoned by harness)
    TJobs JJ;
    auto setj = [&](int i, const float* src, u16* dst, int K, int N, int ldout,
                    int coloff, float scale){
        JJ.j[i] = TJob{src, dst, K, N, ldout, coloff, (K/32)*(N/32), scale};
    };
    setj(0, wq,            wqkT,  512,  512,  512, 0, 0.125f);  // fold 1/sqrt(dh)
    setj(1, wo,            woT,   512,  512,  512, 0, 1.f);
    setj(2, wg,            wgT,   512,  512,  512, 0, 1.f);
    setj(3, fu_w,          WfuT2, 512,  512, 1024, 0, 1.f);     // fuA^T -> cols 0..511
    setj(4, fu_w + 512*512,fuBT,  512,  512,  512, 0, 1.f);     // fuB^T
    int nt = 5*256;
    for (int e = 0; e < 4; ++e){
        setj(5+e, w1 + (size_t)e*512*1024, w1T + (size_t)e*1024*512, 512, 1024, 512, 0, 1.f);
        nt += 512;
    }
    JJ.n = 12;
    setj(9,  w2,                      w2Ts, 1024, 512, 4096, 0,    1.f);
    setj(10, w2 + (size_t)1*1024*512, w2Ts, 1024, 512, 4096, 1024, 1.f);
    setj(11, w2 + (size_t)2*1024*512, w2Ts, 1024, 512, 4096, 2048, 1.f);
    nt += 3*512;
    tconv_all_kernel<<<nt, 256, 0, stream>>>(JJ);
    TJobs J2; J2.n = 1;
    J2.j[0] = TJob{w2 + (size_t)3*1024*512, w2Ts, 1024, 512, 4096, 3072, 512, 1.f};
    tconv_all_kernel<<<512, 256, 0, stream>>>(J2);
    convert_kernel<<<512*512/256, 256, 0, stream>>>(mp_w, mp_wB);
    sgemm_kernel<<<dim3(8,8), 256, 0, stream>>>(wc, wk, wqkT + 512*512, 512, 32); // WckT rows 512..
    sgemm_kernel<<<dim3(8,8), 256, 0, stream>>>(wc, wv, wcvT, 512, 32);           // WcvT
    biasfold_kernel<<<512, 256, 0, stream>>>(fu_b, mp_b, fu_w, fubias);
    // F1^T = (mp_w@fuB)^T into WfuT2 cols 512..1023
    mg64(fuBT, 512, mp_wB, 512, 0, 0, 0, WfuT2 + 512, 1024, 512, 512, 512, 0);

    // ---- main pipeline
    gatepool_kernel<<<(TOK/16)*512/256, 256, 0, stream>>>(x, XFcat);
    mg64 (XFcat, 1024, WfuT2, 1024, fubias, 0, 0, XFU, 512, TOK, 512, 1024, 0);  // xfu
    mg128(XFU, 512, wqkT, 512, 0, 0, 0, QKb, 1024, TOK, 1024, 512, 0);           // [Q|K]
    mg64 (XFU, 512, wcvT, 512, 0, 0, 0, VbT, 8192, TOK, 512, 512, GF_TRANS);     // V^T
    flash_kernel<<<512, 256, 0, stream>>>(QKb, VbT, ATT);
    mg64 (ATT, 512, woT, 512, 0, 0, 0, S3, 512, TOK, 512, 512, 0);               // attn@wo
    rmsnorm_kernel<<<TOK, 256, 0, stream>>>(x, S3, s1, x1h);                     // x1
    router_kernel<<<TOK/4, 256, 0, stream>>>(x1h, wr, br, ROUT);
    mg64 (x1h, 512, wgT, 512, bg, 0, x1h, XG, 512, TOK, 512, 512, GF_GLU);       // xg
    for (int p = 0; p < 2; ++p){
        mg128(XG, 512, w1T + (size_t)p*2048*512, 512, b1 + p*2048, ROUT + p*2, 0,
              Hb, 2048, TOK, 2048, 512, GF_GELU | GF_RSCOL);                     // H (router-scaled)
        mg64 (Hb, 2048, w2Ts + p*2048, 4096, 0, 0, 0,
              MOE, 512, TOK, 512, 2048, p ? GF_ACCUM : GF_F32OUT);               // MOE
    }
    final_kernel<<<TOK, 256, 0, stream>>>(x1h, MOE, ROUT, b2, s2, (float*)d_out);
}

// Round 6
// 588.249 us; speedup vs baseline: 5.1106x; 1.0731x over previous
//
#include <hip/hip_runtime.h>
#include <math.h>

#define B_   4
#define T_   2048
#define D_   512
#define TOK  (B_*T_)      // 8192 tokens
#define TL_  2045         // N_BLOCKS*(T//N_BLOCKS) = 5*409
#define GATE 0.2f         // softmax(...).mean(-1) over same axis == 1/5
#define QSCALE 0.18033688011112043f   // 0.125 * log2(e): S in log2 domain

typedef unsigned short u16;
typedef __attribute__((ext_vector_type(8))) short short8;   // 8 bf16 = 4 VGPRs
typedef __attribute__((ext_vector_type(4))) float f32x4;

static __device__ __forceinline__ u16 f2u(float f){      // fp32 -> bf16 (RNE)
    union { float f; unsigned u; } a; a.f = f;
    unsigned r = a.u + 0x7fffu + ((a.u >> 16) & 1u);
    return (u16)(r >> 16);
}
static __device__ __forceinline__ float u2f(u16 u){
    union { unsigned u; float f; } a; a.u = ((unsigned)u) << 16;
    return a.f;
}
static __device__ __forceinline__ f32x4 mfma16(short8 a, short8 b, f32x4 c){
    return __builtin_amdgcn_mfma_f32_16x16x32_bf16(a, b, c, 0, 0, 0);
}
static __device__ __forceinline__ void glds16(const u16* g, u16* l){
    __builtin_amdgcn_global_load_lds((const __attribute__((address_space(1))) void*)g,
                                     (__attribute__((address_space(3))) void*)l, 16, 0, 0);
}

// ------------------------------------------------------------------
// gate + pool fused: XFcat[:,0:512]=bf16(0.2*x masked), XFcat[:,512:]=bf16(pool)
__global__ __launch_bounds__(256) void gatepool_kernel(
    const float* __restrict__ x, u16* __restrict__ xfcat)
{
    int idx = blockIdx.x*256 + threadIdx.x;
    int d = idx & 511, g = idx >> 9;
    int b = g >> 7, t0 = (g & 127) << 4;
    const float* xp = x + ((size_t)b*2048)*512 + d;
    float v[30];
    #pragma unroll
    for (int j = 0; j < 30; ++j){
        int u = t0 - 7 + j;
        v[j] = (u >= 0 && u < TL_) ? xp[(size_t)u*512] : 0.f;
    }
    float p[31]; p[0] = 0.f;
    #pragma unroll
    for (int j = 0; j < 30; ++j) p[j+1] = p[j] + v[j];
    u16* xc = xfcat + ((size_t)(b*2048 + t0))*1024 + d;
    #pragma unroll
    for (int i = 0; i < 16; ++i){
        int t = t0 + i;
        float sum = p[i+15] - p[i];                 // u in [t-7, t+7]
        int lo = t-7; if (lo < 0) lo = 0;
        int hi = t+7; if (hi > 2047) hi = 2047;
        xc[(size_t)i*1024]       = f2u((t < TL_) ? GATE*v[i+7] : 0.f);
        xc[(size_t)i*1024 + 512] = f2u(GATE * sum / (float)(hi - lo + 1));
    }
}

// ------------------------------------------------------------------
// batched transpose+convert: src fp32 [K,N] -> dst[n*ldout+coloff+k]=bf16(scale*src)
struct TJob { const float* src; u16* dst; int K, N, ldout, coloff, tiles; float scale; };
struct TJobs { TJob j[13]; int n; };

__global__ __launch_bounds__(256) void tconv_all_kernel(TJobs JJ){
    __shared__ float t[32][33];
    int idx = blockIdx.x;
    int jb = 0;
    while (jb < JJ.n - 1 && idx >= JJ.j[jb].tiles){ idx -= JJ.j[jb].tiles; ++jb; }
    TJob J = JJ.j[jb];
    int tX = J.N >> 5;
    int k0 = (idx / tX) * 32, n0 = (idx % tX) * 32;
    int tx = threadIdx.x & 31, ty = threadIdx.x >> 5;
    #pragma unroll
    for (int i = 0; i < 32; i += 8)
        t[ty+i][tx] = J.src[(size_t)(k0+ty+i)*J.N + n0+tx];
    __syncthreads();
    #pragma unroll
    for (int i = 0; i < 32; i += 8)
        J.dst[(size_t)(n0+ty+i)*J.ldout + J.coloff + k0+tx] = f2u(J.scale * t[tx][ty+i]);
}

// fp32 -> bf16 plain convert
__global__ void convert_kernel(const float* __restrict__ in, u16* __restrict__ out){
    int idx = blockIdx.x*256 + threadIdx.x;
    out[idx] = f2u(in[idx]);
}

// fubias[n] = fu_b[n] + sum_d mp_b[d] * fu_w[512+d][n]
__global__ __launch_bounds__(256) void biasfold_kernel(
    const float* __restrict__ fu_b, const float* __restrict__ mp_b,
    const float* __restrict__ fu_w, float* __restrict__ out)
{
    int n = blockIdx.x, tid = threadIdx.x;
    float s = mp_b[tid]*fu_w[(size_t)(512+tid)*512 + n]
            + mp_b[tid+256]*fu_w[(size_t)(768+tid)*512 + n];
    for (int off = 32; off; off >>= 1) s += __shfl_down(s, off);
    __shared__ float ws[4];
    if ((tid & 63) == 0) ws[tid >> 6] = s;
    __syncthreads();
    if (tid == 0) out[n] = fu_b[n] + ws[0]+ws[1]+ws[2]+ws[3];
}

// small fp32 GEMM, N=512: out either fp32 normal (outF) or bf16 transposed (dstT)
__global__ __launch_bounds__(256) void sgemm_kernel(const float* __restrict__ A,
    const float* __restrict__ B, u16* __restrict__ dstT, float* __restrict__ outF, int K){
    __shared__ float As[16][65];
    __shared__ float Bs[16][65];
    int tid = threadIdx.x;
    int tx = tid & 15, ty = tid >> 4;
    int m0 = blockIdx.y*64, n0 = blockIdx.x*64;
    int arow = tid >> 2, akq = (tid & 3) * 4;
    int bk = tid >> 4, bn = (tid & 15) * 4;
    float acc[4][4] = {};
    for (int k0 = 0; k0 < K; k0 += 16){
        const float* Ap = A + (size_t)(m0+arow)*K + k0 + akq;
        As[akq+0][arow]=Ap[0]; As[akq+1][arow]=Ap[1];
        As[akq+2][arow]=Ap[2]; As[akq+3][arow]=Ap[3];
        const float* Bp = B + (size_t)(k0+bk)*512 + n0 + bn;
        Bs[bk][bn+0]=Bp[0]; Bs[bk][bn+1]=Bp[1];
        Bs[bk][bn+2]=Bp[2]; Bs[bk][bn+3]=Bp[3];
        __syncthreads();
        #pragma unroll
        for (int kk = 0; kk < 16; ++kk){
            float av[4], bv[4];
            #pragma unroll
            for (int i=0;i<4;++i) av[i]=As[kk][ty*4+i];
            #pragma unroll
            for (int j=0;j<4;++j) bv[j]=Bs[kk][tx*4+j];
            #pragma unroll
            for (int i=0;i<4;++i)
                #pragma unroll
                for (int j=0;j<4;++j) acc[i][j] += av[i]*bv[j];
        }
        __syncthreads();
    }
    if (outF){
        #pragma unroll
        for (int i=0;i<4;++i)
            #pragma unroll
            for (int j=0;j<4;++j)
                outF[(size_t)(m0+ty*4+i)*512 + n0+tx*4+j] = acc[i][j];
    } else {
        #pragma unroll
        for (int i=0;i<4;++i)
            #pragma unroll
            for (int j=0;j<4;++j)
                dstT[(size_t)(n0+tx*4+j)*512 + m0+ty*4+i] = f2u(acc[i][j]);
    }
}

// ------------------------------------------------------------------
// bf16 MFMA GEMM: C[M,N] = op(A[M,K] @ Bt[N,K]^T + bias), MTx128 tile, BK=64.
#define GF_GELU   1
#define GF_ACCUM  2
#define GF_RSCOL  4
#define GF_GLU    8
#define GF_F32OUT 16
#define GF_QKV    32   // n0<1024: plain bf16 -> Cp; n0>=1024: transposed -> Cp2

template<int MT>
__global__ __launch_bounds__(256) void mgemm_kernel(
    const u16* __restrict__ A, int lda, const u16* __restrict__ Bt, int ldb,
    const float* __restrict__ bias, const float* __restrict__ rs,
    const u16* __restrict__ glu, void* __restrict__ Cp, int ldc,
    u16* __restrict__ Cp2, int K, int flags)
{
    constexpr int MI = MT/32;            // m-tiles per wave (16 rows each)
    __shared__ u16 As[MT*64];
    __shared__ u16 Bs[128*64];
    int tid = threadIdx.x;
    int wave = tid >> 6, lane = tid & 63;
    int n16 = lane & 15, quad = lane >> 4;
    int m0 = blockIdx.y * MT, n0 = blockIdx.x * 128;
    int wr = (wave >> 1) * (MT/2), wc = (wave & 1) * 64;

    f32x4 acc[MI][4] = {};

    for (int k0 = 0; k0 < K; k0 += 64){
        #pragma unroll
        for (int i = 0; i < MT/32; ++i){
            int s = i*256 + tid;
            int row = s >> 3, g = (s & 7) ^ (row & 7);
            glds16(A + (size_t)(m0+row)*lda + k0 + g*8, As + (size_t)s*8);
        }
        #pragma unroll
        for (int i = 0; i < 4; ++i){
            int s = i*256 + tid;
            int row = s >> 3, g = (s & 7) ^ (row & 7);
            glds16(Bt + (size_t)(n0+row)*ldb + k0 + g*8, Bs + (size_t)s*8);
        }
        __syncthreads();
        #pragma unroll
        for (int ks = 0; ks < 2; ++ks){
            short8 af[MI], bf[4];
            #pragma unroll
            for (int mi = 0; mi < MI; ++mi){
                int row = wr + mi*16 + n16;
                int g = (ks*4 + quad) ^ (row & 7);
                af[mi] = *(const short8*)&As[row*64 + g*8];
            }
            #pragma unroll
            for (int ni = 0; ni < 4; ++ni){
                int row = wc + ni*16 + n16;
                int g = (ks*4 + quad) ^ (row & 7);
                bf[ni] = *(const short8*)&Bs[row*64 + g*8];
            }
            #pragma unroll
            for (int mi = 0; mi < MI; ++mi)
                #pragma unroll
                for (int ni = 0; ni < 4; ++ni)
                    acc[mi][ni] = mfma16(af[mi], bf[ni], acc[mi][ni]);
        }
        __syncthreads();
    }

    if ((flags & GF_QKV) && n0 >= 1024){
        // V region: store transposed into Cp2 [512, 8192]
        #pragma unroll
        for (int mi = 0; mi < MI; ++mi){
            int row0 = m0 + wr + mi*16 + quad*4;
            #pragma unroll
            for (int ni = 0; ni < 4; ++ni){
                int col = n0 + wc + ni*16 + n16 - 1024;
                ushort4 h4;
                h4.x = f2u(acc[mi][ni][0]); h4.y = f2u(acc[mi][ni][1]);
                h4.z = f2u(acc[mi][ni][2]); h4.w = f2u(acc[mi][ni][3]);
                *(ushort4*)&Cp2[(size_t)col*8192 + row0] = h4;
            }
        }
        return;
    }

    #pragma unroll
    for (int mi = 0; mi < MI; ++mi){
        #pragma unroll
        for (int reg = 0; reg < 4; ++reg){
            int row = m0 + wr + mi*16 + quad*4 + reg;
            #pragma unroll
            for (int ni = 0; ni < 4; ++ni){
                int col = n0 + wc + ni*16 + n16;
                float v = acc[mi][ni][reg];
                if (bias) v += bias[col];
                if (flags & GF_GELU)  v = 0.5f*v*(1.f + erff(v*0.70710678118f));
                if (flags & GF_GLU)   v = u2f(glu[(size_t)row*512 + col]) / (1.f + __expf(-v));
                if (flags & GF_RSCOL) v *= rs[(size_t)row*4 + (col >> 10)];
                size_t ci = (size_t)row*ldc + col;
                if (flags & GF_ACCUM)       ((float*)Cp)[ci] += v;
                else if (flags & GF_F32OUT) ((float*)Cp)[ci]  = v;
                else                        ((u16*)Cp)[ci]    = f2u(v);
            }
        }
    }
}

// ------------------------------------------------------------------
// MFMA flash attention (S^T formulation), causal, dh=64, 8 heads.
// 128-row Q-tile/block; wave owns 2 groups of 16 q-rows. S^T = K·Q^T puts each
// q-row's scores in ONE lane (16 in-lane values + 2 shfls per reduction).
// Q pre-scaled by 0.125*log2e -> exp2f softmax. P stored as packed b64 writes.
__global__ __launch_bounds__(256) void flash_kernel(
    const u16* __restrict__ QK,   // [8192,1024]: cols 0..511 Q', 512..1023 K
    const u16* __restrict__ VT,   // [512,8192]
    u16* __restrict__ O)          // [8192,512]
{
    int bid = blockIdx.x;
    int qt = 15 - (bid >> 5);          // global heavy-first
    int bh = bid & 31;
    int h = bh & 7, b = bh >> 3;
    __shared__ u16 Ks[64*64];
    __shared__ u16 Vt[64*64];
    __shared__ u16 Ps[4][32*64];
    int tid = threadIdx.x;
    int wave = tid >> 6, lane = tid & 63;
    int n16 = lane & 15, quad = lane >> 4;
    size_t btok = (size_t)b*2048;
    size_t tok0 = btok + qt*128;

    // Q fragments (B-operand for K·Q^T): lane n16 = q-col, quad*8 = d-offset
    short8 qf[2][2];
    #pragma unroll
    for (int g = 0; g < 2; ++g)
        #pragma unroll
        for (int ks = 0; ks < 2; ++ks)
            qf[g][ks] = *(const short8*)&QK[(tok0 + wave*32 + g*16 + n16)*1024
                                           + h*64 + ks*32 + quad*8];

    int qlo[2];  qlo[0] = qt*128 + wave*32; qlo[1] = qlo[0] + 16;
    int qrow[2]; qrow[0] = qlo[0] + n16;    qrow[1] = qlo[1] + n16;
    float m_st[2] = {-3.0e38f, -3.0e38f}, l_st[2] = {0.f, 0.f};
    f32x4 ov[2][4] = {};

    int nkt = 2*qt + 2;
    for (int kt = 0; kt < nkt; ++kt){
        __syncthreads();
        {   // stage K and V^T tiles (swizzled groups of 8 u16)
            int r = tid >> 2;
            int g0 = (tid & 3) * 2;
            const uint4* kp = (const uint4*)&QK[(btok + kt*64 + r)*1024 + 512 + h*64 + g0*8];
            uint4 ka = kp[0], kb = kp[1];
            *(uint4*)&Ks[r*64 + ((g0  ) ^ (r&7))*8] = ka;
            *(uint4*)&Ks[r*64 + ((g0+1) ^ (r&7))*8] = kb;
            const uint4* vp = (const uint4*)&VT[(size_t)(h*64 + r)*8192 + btok + kt*64 + g0*8];
            uint4 va = vp[0], vb = vp[1];
            *(uint4*)&Vt[r*64 + ((g0  ) ^ (r&7))*8] = va;
            *(uint4*)&Vt[r*64 + ((g0+1) ^ (r&7))*8] = vb;
        }
        __syncthreads();

        bool act[2];
        #pragma unroll
        for (int g = 0; g < 2; ++g){
            act[g] = (kt*64 <= qlo[g] + 15);
            if (!act[g]) continue;
            // S^T tile: A = K-rows (ct), B = Q-group; lane holds rows k=ct*16+quad*4+reg, col q=n16
            f32x4 st[4];
            #pragma unroll
            for (int ct = 0; ct < 4; ++ct){
                f32x4 a = {};
                #pragma unroll
                for (int ks = 0; ks < 2; ++ks){
                    short8 kf = *(const short8*)&Ks[(ct*16+n16)*64 + (((ks*4+quad) ^ (n16&7))*8)];
                    a = mfma16(kf, qf[g][ks], a);
                }
                st[ct] = a;
            }
            if (kt*64 + 63 > qlo[g]){          // diagonal: causal mask
                #pragma unroll
                for (int ct = 0; ct < 4; ++ct){
                    int kb0 = kt*64 + ct*16 + quad*4;
                    #pragma unroll
                    for (int r = 0; r < 4; ++r)
                        if (kb0 + r > qrow[g]) st[ct][r] = -3.0e38f;
                }
            }
            // row (q) reduction: 15 in-lane max + 2 shfls
            float mx = fmaxf(fmaxf(fmaxf(st[0][0],st[0][1]),fmaxf(st[0][2],st[0][3])),
                       fmaxf(fmaxf(fmaxf(st[1][0],st[1][1]),fmaxf(st[1][2],st[1][3])),
                       fmaxf(fmaxf(fmaxf(st[2][0],st[2][1]),fmaxf(st[2][2],st[2][3])),
                             fmaxf(fmaxf(st[3][0],st[3][1]),fmaxf(st[3][2],st[3][3])))));
            mx = fmaxf(mx, __shfl_xor(mx, 16));
            mx = fmaxf(mx, __shfl_xor(mx, 32));
            float mn = fmaxf(m_st[g], mx);
            float al = exp2f(m_st[g] - mn);
            m_st[g] = mn;
            float sum = 0.f;
            #pragma unroll
            for (int ct = 0; ct < 4; ++ct)
                #pragma unroll
                for (int r = 0; r < 4; ++r){
                    float p = exp2f(st[ct][r] - mn);
                    st[ct][r] = p; sum += p;
                }
            sum += __shfl_xor(sum, 16);
            sum += __shfl_xor(sum, 32);
            l_st[g] = l_st[g]*al + sum;
            // P store: q-major rows, packed b64 (reg-consecutive k)
            int qr = g*16 + n16;
            #pragma unroll
            for (int ct = 0; ct < 4; ++ct){
                ushort4 h4;
                h4.x = f2u(st[ct][0]); h4.y = f2u(st[ct][1]);
                h4.z = f2u(st[ct][2]); h4.w = f2u(st[ct][3]);
                int goff = ct*2 + (quad >> 1);
                *(ushort4*)&Ps[wave][qr*64 + ((goff ^ (qr&7))*8) + (quad&1)*4] = h4;
            }
            // rescale O: alpha for q=quad*4+r via bpermute from lane holding it
            #pragma unroll
            for (int r = 0; r < 4; ++r){
                float aa = __shfl(al, quad*4 + r);
                #pragma unroll
                for (int dt = 0; dt < 4; ++dt) ov[g][dt][r] *= aa;
            }
        }
        // O += P V  (same-wave LDS write->read, program order)
        #pragma unroll
        for (int g = 0; g < 2; ++g){
            if (!act[g]) continue;
            short8 ap[2];
            int row = g*16 + n16;
            #pragma unroll
            for (int ks = 0; ks < 2; ++ks)
                ap[ks] = *(const short8*)&Ps[wave][row*64 + (((ks*4+quad) ^ (row&7))*8)];
            #pragma unroll
            for (int dt = 0; dt < 4; ++dt)
                #pragma unroll
                for (int ks = 0; ks < 2; ++ks){
                    short8 bv = *(const short8*)&Vt[(dt*16+n16)*64 + (((ks*4+quad) ^ (n16&7))*8)];
                    ov[g][dt] = mfma16(ap[ks], bv, ov[g][dt]);
                }
        }
    }
    #pragma unroll
    for (int g = 0; g < 2; ++g)
        #pragma unroll
        for (int r = 0; r < 4; ++r){
            float li = __shfl(l_st[g], quad*4 + r);
            float inv = 1.f / li;
            size_t row = tok0 + wave*32 + g*16 + quad*4 + r;
            #pragma unroll
            for (int dt = 0; dt < 4; ++dt)
                O[row*512 + h*64 + dt*16 + n16] = f2u(ov[g][dt][r] * inv);
        }
}

// ------------------------------------------------------------------
// x1h = bf16( rmsnorm(x + y_bf16) * scale )
__global__ __launch_bounds__(256) void rmsnorm_kernel(
    const float* __restrict__ x, const u16* __restrict__ y,
    const float* __restrict__ scale, u16* __restrict__ out)
{
    int tok = blockIdx.x, tid = threadIdx.x;
    size_t base = (size_t)tok * 512;
    float v0 = x[base+tid]     + u2f(y[base+tid]);
    float v1 = x[base+tid+256] + u2f(y[base+tid+256]);
    float ss = v0*v0 + v1*v1;
    for (int off = 32; off; off >>= 1) ss += __shfl_down(ss, off);
    __shared__ float ws[4];
    if ((tid & 63) == 0) ws[tid >> 6] = ss;
    __syncthreads();
    float rstd = rsqrtf((ws[0]+ws[1]+ws[2]+ws[3])*(1.f/512.f) + 1e-6f);
    out[base+tid]     = f2u(scale[tid]     * v0 * rstd);
    out[base+tid+256] = f2u(scale[tid+256] * v1 * rstd);
}

// out_fp32 = rmsnorm(x1h + moe + ROUT@b2) * scale
__global__ __launch_bounds__(256) void final_kernel(
    const u16* __restrict__ x1, const float* __restrict__ moe,
    const float* __restrict__ rout, const float* __restrict__ b2,
    const float* __restrict__ scale, float* __restrict__ out)
{
    int tok = blockIdx.x, tid = threadIdx.x;
    size_t base = (size_t)tok * 512;
    float r0 = rout[tok*4+0], r1 = rout[tok*4+1], r2 = rout[tok*4+2], r3 = rout[tok*4+3];
    float bb0 = r0*b2[tid]     + r1*b2[512+tid]     + r2*b2[1024+tid]     + r3*b2[1536+tid];
    float bb1 = r0*b2[tid+256] + r1*b2[768+tid]     + r2*b2[1280+tid]     + r3*b2[1792+tid];
    float v0 = u2f(x1[base+tid])     + moe[base+tid]     + bb0;
    float v1 = u2f(x1[base+tid+256]) + moe[base+tid+256] + bb1;
    float ss = v0*v0 + v1*v1;
    for (int off = 32; off; off >>= 1) ss += __shfl_down(ss, off);
    __shared__ float ws[4];
    if ((tid & 63) == 0) ws[tid >> 6] = ss;
    __syncthreads();
    float rstd = rsqrtf((ws[0]+ws[1]+ws[2]+ws[3])*(1.f/512.f) + 1e-6f);
    out[base+tid]     = scale[tid]     * v0 * rstd;
    out[base+tid+256] = scale[tid+256] * v1 * rstd;
}

// router: softmax(x1h @ wr + br), one wave per token
__global__ __launch_bounds__(256) void router_kernel(
    const u16* __restrict__ x1, const float* __restrict__ wr,
    const float* __restrict__ br, float* __restrict__ rout)
{
    int wid = threadIdx.x >> 6, lane = threadIdx.x & 63;
    int tok = blockIdx.x*4 + wid;
    const u16* xp = x1 + (size_t)tok*512;
    float p0=0.f, p1=0.f, p2=0.f, p3=0.f;
    for (int d = lane; d < 512; d += 64){
        float xv = u2f(xp[d]);
        p0 += xv*wr[d*4+0]; p1 += xv*wr[d*4+1];
        p2 += xv*wr[d*4+2]; p3 += xv*wr[d*4+3];
    }
    for (int off = 32; off; off >>= 1){
        p0 += __shfl_down(p0,off); p1 += __shfl_down(p1,off);
        p2 += __shfl_down(p2,off); p3 += __shfl_down(p3,off);
    }
    if (lane == 0){
        p0 += br[0]; p1 += br[1]; p2 += br[2]; p3 += br[3];
        float mx = fmaxf(fmaxf(p0,p1), fmaxf(p2,p3));
        float e0=__expf(p0-mx), e1=__expf(p1-mx), e2=__expf(p2-mx), e3=__expf(p3-mx);
        float inv = 1.f/(e0+e1+e2+e3);
        rout[tok*4+0]=e0*inv; rout[tok*4+1]=e1*inv;
        rout[tok*4+2]=e2*inv; rout[tok*4+3]=e3*inv;
    }
}

// ------------------------------------------------------------------
extern "C" void kernel_launch(void* const* d_in, const int* in_sizes, int n_in,
                              void* d_out, int out_size, void* d_ws, size_t ws_size,
                              hipStream_t stream)
{
    const float* x    = (const float*)d_in[0];
    const float* mp_w = (const float*)d_in[3];
    const float* mp_b = (const float*)d_in[4];
    const float* fu_w = (const float*)d_in[5];
    const float* fu_b = (const float*)d_in[6];
    const float* wc   = (const float*)d_in[7];
    const float* wk   = (const float*)d_in[8];
    const float* wv   = (const float*)d_in[9];
    const float* wq   = (const float*)d_in[10];
    const float* wo   = (const float*)d_in[11];
    const float* s1   = (const float*)d_in[12];
    const float* s2   = (const float*)d_in[13];
    const float* wr   = (const float*)d_in[14];
    const float* br   = (const float*)d_in[15];
    const float* wg   = (const float*)d_in[16];
    const float* bg   = (const float*)d_in[17];
    const float* w1   = (const float*)d_in[18];
    const float* b1   = (const float*)d_in[19];
    const float* w2   = (const float*)d_in[20];
    const float* b2   = (const float*)d_in[21];

    char* wsb = (char*)d_ws;
    const size_t MB = 1024*1024;
    const size_t KB512 = 512*1024;
    // persistent (14 MB)
    u16*   wqkvT  = (u16*)(wsb + 0);                 // [1536,512]: wq'(x q-scale) | wc@wk | wc@wv
    u16*   woT    = (u16*)(wsb + 3*KB512);           // [512,512]
    u16*   wgT    = (u16*)(wsb + 4*KB512);           // [512,512]
    u16*   WfuT2  = (u16*)(wsb + 5*KB512);           // [512,1024]
    u16*   fuBT   = (u16*)(wsb + 7*KB512);           // [512,512]
    u16*   mp_wB  = (u16*)(wsb + 8*KB512);           // [512,512] row-major
    u16*   w1T    = (u16*)(wsb + 9*KB512);           // [4096,512]
    u16*   w2Ts   = (u16*)(wsb + 17*KB512);          // [512,4096]
    float* WcvF   = (float*)(wsb + 25*KB512);        // [512,512] fp32
    float* fubias = (float*)(wsb + 27*KB512);        // 512
    float* ROUT   = (float*)(wsb + 27*KB512 + 4096); // 8192x4
    // big rotating buffers (high-water 86 MB)
    u16*   XFcat = (u16*)(wsb + 14*MB);              // [8192,1024] (dead after xfu)
    float* MOE   = (float*)(wsb + 14*MB);            // [8192,512] fp32 (w2 phase)
    u16*   S3    = (u16*)(wsb + 14*MB);              // [8192,512] (wo out)
    u16*   XFU   = (u16*)(wsb + 30*MB);              // [8192,512]
    u16*   XG    = (u16*)(wsb + 30*MB);
    u16*   QKb   = (u16*)(wsb + 38*MB);              // [8192,1024] (dead after flash)
    u16*   Hb    = (u16*)(wsb + 38*MB);              // [8192,4096 over pairs? [8192,2048]x32MB]
    u16*   ATT   = (u16*)(wsb + 54*MB);              // [8192,512] (dead before w1)
    u16*   VbT   = (u16*)(wsb + 70*MB);              // [512,8192]
    u16*   x1h   = (u16*)(wsb + 78*MB);              // [8192,512]

    auto mg128 = [&](const u16* A, int lda, const u16* Bt, int ldb, const float* bias,
                     const float* rs, const u16* glu, void* C, int ldc, u16* C2,
                     int M, int N, int K, int flags){
        dim3 g(N/128, M/128);
        mgemm_kernel<128><<<g, 256, 0, stream>>>(A, lda, Bt, ldb, bias, rs, glu, C, ldc, C2, K, flags);
    };
    auto mg64 = [&](const u16* A, int lda, const u16* Bt, int ldb, const float* bias,
                    const float* rs, const u16* glu, void* C, int ldc, u16* C2,
                    int M, int N, int K, int flags){
        dim3 g(N/128, M/64);
        mgemm_kernel<64><<<g, 256, 0, stream>>>(A, lda, Bt, ldb, bias, rs, glu, C, ldc, C2, K, flags);
    };

    // ---- prepass
    TJobs JJ; JJ.n = 13;
    auto setj = [&](int i, const float* src, u16* dst, int K, int N, int ldout,
                    int coloff, float scale){
        JJ.j[i] = TJob{src, dst, K, N, ldout, coloff, (K/32)*(N/32), scale};
    };
    setj(0, wq,            wqkvT, 512,  512,  512, 0, QSCALE);   // Q' = wq * 0.125*log2e
    setj(1, wo,            woT,   512,  512,  512, 0, 1.f);
    setj(2, wg,            wgT,   512,  512,  512, 0, 1.f);
    setj(3, fu_w,          WfuT2, 512,  512, 1024, 0, 1.f);
    setj(4, fu_w + 512*512,fuBT,  512,  512,  512, 0, 1.f);
    for (int e = 0; e < 4; ++e){
        setj(5+e, w1 + (size_t)e*512*1024, w1T + (size_t)e*1024*512, 512, 1024, 512, 0, 1.f);
        setj(9+e, w2 + (size_t)e*1024*512, w2Ts + (size_t)e*1024, 1024, 512, 4096, 0, 1.f);
    }
    int nt = 5*256 + 4*512 + 4*512;
    tconv_all_kernel<<<nt, 256, 0, stream>>>(JJ);
    convert_kernel<<<512*512/256, 256, 0, stream>>>(mp_w, mp_wB);
    sgemm_kernel<<<dim3(8,8), 256, 0, stream>>>(wc, wk, wqkvT + 512*512, nullptr, 32); // Wck^T
    sgemm_kernel<<<dim3(8,8), 256, 0, stream>>>(wc, wv, wqkvT + 1024*512, nullptr, 32);// Wcv^T
    biasfold_kernel<<<512, 256, 0, stream>>>(fu_b, mp_b, fu_w, fubias);
    // (mp_w @ fuB)^T -> WfuT2 cols 512..1023
    mg64(fuBT, 512, mp_wB, 512, 0, 0, 0, WfuT2 + 512, 1024, 0, 512, 512, 512, 0);
    (void)WcvF;

    // ---- main pipeline
    gatepool_kernel<<<(TOK/16)*512/256, 256, 0, stream>>>(x, XFcat);
    mg64 (XFcat, 1024, WfuT2, 1024, fubias, 0, 0, XFU, 512, 0, TOK, 512, 1024, 0);  // xfu
    mg64 (XFU, 512, wqkvT, 512, 0, 0, 0, QKb, 1024, VbT, TOK, 1536, 512, GF_QKV);   // Q'|K -> QKb, V^T -> VbT
    flash_kernel<<<512, 256, 0, stream>>>(QKb, VbT, ATT);
    mg64 (ATT, 512, woT, 512, 0, 0, 0, S3, 512, 0, TOK, 512, 512, 0);               // attn@wo
    rmsnorm_kernel<<<TOK, 256, 0, stream>>>(x, S3, s1, x1h);                        // x1
    router_kernel<<<TOK/4, 256, 0, stream>>>(x1h, wr, br, ROUT);
    mg64 (x1h, 512, wgT, 512, bg, 0, x1h, XG, 512, 0, TOK, 512, 512, GF_GLU);       // xg
    for (int p = 0; p < 2; ++p){
        mg128(XG, 512, w1T + (size_t)p*2048*512, 512, b1 + p*2048, ROUT + p*2, 0,
              Hb, 2048, 0, TOK, 2048, 512, GF_GELU | GF_RSCOL);                     // H (router-scaled)
        mg64 (Hb, 2048, w2Ts + p*2048, 4096, 0, 0, 0,
              MOE, 512, 0, TOK, 512, 2048, p ? GF_ACCUM : GF_F32OUT);               // MOE
    }
    final_kernel<<<TOK, 256, 0, stream>>>(x1h, MOE, ROUT, b2, s2, (float*)d_out);
}